// Round 7
// baseline (2110.321 us; speedup 1.0000x reference)
//
#include <hip/hip_runtime.h>

// ---------------------------------------------------------------------------
// Transformer (enc-dec, D=512, H=8, N=6, DFF=2048, B=4, S=T=1024, V=32000)
// PIPE3 GEMM fleet (128x64, BK=64, 3 LDS slots, counted vmcnt(6), T2 swizzle).
// Generator: PIPE3 + T1 XCD swizzle + LDS-transposed dwordx4 epilogue.
// Fused flash attention; fp32 residual/LN; bulk weight transposes.
// ---------------------------------------------------------------------------

typedef __bf16 bf16x8 __attribute__((ext_vector_type(8)));
typedef __bf16 bf16x4 __attribute__((ext_vector_type(4)));
typedef float  f32x4  __attribute__((ext_vector_type(4)));

__device__ __forceinline__ void gload_lds16(const void* g, void* l) {
  __builtin_amdgcn_global_load_lds((__attribute__((address_space(1))) void*)g,
                                   (__attribute__((address_space(3))) void*)l,
                                   16, 0, 0);
}

__device__ __forceinline__ void hard_barrier() {
  asm volatile("" ::: "memory");
  __builtin_amdgcn_sched_barrier(0);
  __builtin_amdgcn_s_barrier();
  __builtin_amdgcn_sched_barrier(0);
  asm volatile("" ::: "memory");
}

// ---------------------------------------------------------------------------
// PIPE3 GEMM: C = A[M,K] @ BT[N,K]^T + bias. A,BT bf16 row-major.
// 256 thr, 4 waves (2x2), tile 128x64, BK=64. 3 swizzled LDS slots.
// EPI 0: C fp32 + bias. EPI 1: C bf16 + bias + ReLU. EPI 2: qkv head routing.
template<int EPI>
__global__ __launch_bounds__(256)
void gemm_kernel(const __bf16* __restrict__ A, int lda,
                 const __bf16* __restrict__ BT, int ldb,
                 void* __restrict__ Cv, int ldc,
                 const float* __restrict__ bias, int K,
                 __bf16* __restrict__ qb, __bf16* __restrict__ kb,
                 __bf16* __restrict__ vt, int zoff)
{
  constexpr int BM = 128, BN = 64, BK = 64;
  constexpr int WM = 64, WN = 32, FM = 4, FN = 2;
  constexpr int LA = (BM * BK) / 2048;
  constexpr int LB = (BN * BK) / 2048;
  constexpr int SLOT = (BM + BN) * BK;
  __shared__ __bf16 lds[3 * SLOT];             // 72 KB
  const int tid  = threadIdx.x;
  const int lane = tid & 63, wave = tid >> 6;
  const int wr = wave >> 1, wc = wave & 1;
  const int bm = blockIdx.x * BM, bn = blockIdx.y * BN;

  auto stage = [&](int slot, int kt) {
    const char* Ag = (const char*)A;
    const char* Bg = (const char*)BT;
    char* base = (char*)(lds + slot * SLOT);
    const long long k0b = (long long)kt * (BK * 2);
#pragma unroll
    for (int i = 0; i < LA; i++) {
      int t = tid + i * 256;
      int row = t >> 3, cb = (t & 7) << 4;
      int src = cb ^ ((row & 7) << 4);
      gload_lds16(Ag + ((long long)(bm + row) * lda) * 2 + k0b + src, base + t * 16);
    }
#pragma unroll
    for (int i = 0; i < LB; i++) {
      int t = tid + i * 256;
      int row = t >> 3, cb = (t & 7) << 4;
      int src = cb ^ ((row & 7) << 4);
      gload_lds16(Bg + ((long long)(bn + row) * ldb) * 2 + k0b + src,
                  base + BM * BK * 2 + t * 16);
    }
  };

  f32x4 acc[FM][FN] = {};
  const int NT = K / BK;

  stage(0, 0);
  stage(1, 1);

  for (int t = 0; t < NT; t++) {
    if (t < NT - 1) {
      asm volatile("s_waitcnt vmcnt(6)" ::: "memory");
    } else {
      asm volatile("s_waitcnt vmcnt(0)" ::: "memory");
    }
    hard_barrier();
    if (t + 2 < NT) stage((t + 2) % 3, t + 2);
    const char* sA = (const char*)(lds + (t % 3) * SLOT);
    const char* sB = sA + BM * BK * 2;
#pragma unroll
    for (int kk = 0; kk < 2; kk++) {
      const int g = kk * 64 + (lane >> 4) * 16;
      bf16x8 af[FM], bfr[FN];
#pragma unroll
      for (int i = 0; i < FM; i++) {
        int row = wr * WM + i * 16 + (lane & 15);
        af[i] = *(const bf16x8*)(sA + row * 128 + (g ^ ((row & 7) << 4)));
      }
#pragma unroll
      for (int j = 0; j < FN; j++) {
        int row = wc * WN + j * 16 + (lane & 15);
        bfr[j] = *(const bf16x8*)(sB + row * 128 + (g ^ ((row & 7) << 4)));
      }
      __builtin_amdgcn_s_setprio(1);
#pragma unroll
      for (int i = 0; i < FM; i++)
#pragma unroll
        for (int j = 0; j < FN; j++)
          acc[i][j] = __builtin_amdgcn_mfma_f32_16x16x32_bf16(af[i], bfr[j], acc[i][j], 0, 0, 0);
      __builtin_amdgcn_s_setprio(0);
    }
  }

#pragma unroll
  for (int i = 0; i < FM; i++) {
#pragma unroll
    for (int j = 0; j < FN; j++) {
      int row0 = bm + wr * WM + i * 16 + (lane >> 4) * 4;
      int col  = bn + wc * WN + j * 16 + (lane & 15);
      float bv = bias ? bias[col] : 0.f;
      if constexpr (EPI == 2) {
        int z = zoff + (col >> 9);
        int cw = col & 511;
        int b = row0 >> 10, s = row0 & 1023;
        int h = cw >> 6, dk = cw & 63;
        long long bh = b * 8 + h;
        if (z == 2) {
          bf16x4 vv;
#pragma unroll
          for (int r = 0; r < 4; r++) vv[r] = (__bf16)(acc[i][j][r] + bv);
          *(bf16x4*)(vt + (bh << 16) + (dk << 10) + s) = vv;
        } else {
          __bf16* dst = (z == 0) ? qb : kb;
          float sc = (z == 0) ? 0.125f : 1.0f;
#pragma unroll
          for (int r = 0; r < 4; r++)
            dst[(bh << 16) + ((long long)(s + r) << 6) + dk] = (__bf16)((acc[i][j][r] + bv) * sc);
        }
      } else if constexpr (EPI == 1) {
        __bf16* C = (__bf16*)Cv;
#pragma unroll
        for (int r = 0; r < 4; r++)
          C[(long long)(row0 + r) * ldc + col] = (__bf16)fmaxf(acc[i][j][r] + bv, 0.f);
      } else {
        float* C = (float*)Cv;
#pragma unroll
        for (int r = 0; r < 4; r++)
          C[(long long)(row0 + r) * ldc + col] = acc[i][j][r] + bv;
      }
    }
  }
}

// ---------------------------------------------------------------------------
// Generator GEMM: PIPE3 core + T1 XCD-chunked block swizzle + LDS-transposed
// dwordx4 epilogue (256-B store segments). 1-D grid, nwg % 8 == 0.
__global__ __launch_bounds__(256)
void gemm_gen_kernel(const __bf16* __restrict__ A, int lda,
                     const __bf16* __restrict__ BT, int ldb,
                     float* __restrict__ C, int ldc,
                     const float* __restrict__ bias, int K, int nbx)
{
  constexpr int BM = 128, BN = 64, BK = 64;
  constexpr int WM = 64, WN = 32, FM = 4, FN = 2;
  constexpr int LA = (BM * BK) / 2048;
  constexpr int LB = (BN * BK) / 2048;
  constexpr int SLOT = (BM + BN) * BK;
  __shared__ __bf16 lds[3 * SLOT];             // 72 KB
  const int tid  = threadIdx.x;
  const int lane = tid & 63, wave = tid >> 6;
  const int wr = wave >> 1, wc = wave & 1;
  // T1: each XCD gets a contiguous chunk; same-B-panel row-blocks adjacent.
  const int cpx = gridDim.x >> 3;
  const int wg  = (blockIdx.x & 7) * cpx + (blockIdx.x >> 3);
  const int bm  = (wg % nbx) * BM;
  const int bn  = (wg / nbx) * BN;

  auto stage = [&](int slot, int kt) {
    const char* Ag = (const char*)A;
    const char* Bg = (const char*)BT;
    char* base = (char*)(lds + slot * SLOT);
    const long long k0b = (long long)kt * (BK * 2);
#pragma unroll
    for (int i = 0; i < LA; i++) {
      int t = tid + i * 256;
      int row = t >> 3, cb = (t & 7) << 4;
      int src = cb ^ ((row & 7) << 4);
      gload_lds16(Ag + ((long long)(bm + row) * lda) * 2 + k0b + src, base + t * 16);
    }
#pragma unroll
    for (int i = 0; i < LB; i++) {
      int t = tid + i * 256;
      int row = t >> 3, cb = (t & 7) << 4;
      int src = cb ^ ((row & 7) << 4);
      gload_lds16(Bg + ((long long)(bn + row) * ldb) * 2 + k0b + src,
                  base + BM * BK * 2 + t * 16);
    }
  };

  f32x4 acc[FM][FN] = {};
  const int NT = K / BK;

  stage(0, 0);
  stage(1, 1);

  for (int t = 0; t < NT; t++) {
    if (t < NT - 1) {
      asm volatile("s_waitcnt vmcnt(6)" ::: "memory");
    } else {
      asm volatile("s_waitcnt vmcnt(0)" ::: "memory");
    }
    hard_barrier();
    if (t + 2 < NT) stage((t + 2) % 3, t + 2);
    const char* sA = (const char*)(lds + (t % 3) * SLOT);
    const char* sB = sA + BM * BK * 2;
#pragma unroll
    for (int kk = 0; kk < 2; kk++) {
      const int g = kk * 64 + (lane >> 4) * 16;
      bf16x8 af[FM], bfr[FN];
#pragma unroll
      for (int i = 0; i < FM; i++) {
        int row = wr * WM + i * 16 + (lane & 15);
        af[i] = *(const bf16x8*)(sA + row * 128 + (g ^ ((row & 7) << 4)));
      }
#pragma unroll
      for (int j = 0; j < FN; j++) {
        int row = wc * WN + j * 16 + (lane & 15);
        bfr[j] = *(const bf16x8*)(sB + row * 128 + (g ^ ((row & 7) << 4)));
      }
      __builtin_amdgcn_s_setprio(1);
#pragma unroll
      for (int i = 0; i < FM; i++)
#pragma unroll
        for (int j = 0; j < FN; j++)
          acc[i][j] = __builtin_amdgcn_mfma_f32_16x16x32_bf16(af[i], bfr[j], acc[i][j], 0, 0, 0);
      __builtin_amdgcn_s_setprio(0);
    }
  }

  // ---- LDS-transposed epilogue: 128x64 fp32 tile, stride 68 floats ----
  __syncthreads();                             // all LDS reads of last tile done
  float* ct = (float*)lds;                     // 128*68*4 = 34816 B <= 72 KB
#pragma unroll
  for (int i = 0; i < FM; i++) {
#pragma unroll
    for (int j = 0; j < FN; j++) {
      int lrow = wr * WM + i * 16 + (lane >> 4) * 4;
      int lcol = wc * WN + j * 16 + (lane & 15);
      float bv = bias[bn + lcol];
#pragma unroll
      for (int r = 0; r < 4; r++)
        ct[(lrow + r) * 68 + lcol] = acc[i][j][r] + bv;
    }
  }
  __syncthreads();
  // 128 rows x 16 f32x4 = 2048 vector stores over 256 threads = 8 iterations
#pragma unroll
  for (int it = 0; it < 8; it++) {
    int idx = tid + it * 256;                  // 0..2047
    int row = idx >> 4, c4 = (idx & 15) * 4;
    f32x4 v = *(const f32x4*)(ct + row * 68 + c4);
    *(f32x4*)(C + (long long)(bm + row) * ldc + bn + c4) = v;
  }
}

// ---------------------------------------------------------------------------
// Flash attention (unchanged): per block one (bh, 64-row q-tile).
template<int CAUSAL>
__global__ __launch_bounds__(256)
void flash_kernel(const __bf16* __restrict__ qb, const __bf16* __restrict__ kb,
                  const __bf16* __restrict__ vt, const int* __restrict__ smask,
                  __bf16* __restrict__ Ob)
{
  __shared__ __bf16 lK[2 * 128 * 64];
  __shared__ __bf16 lV[2 * 64 * 128];
  __shared__ __bf16 lP[4][16 * 128];
  const int bh = blockIdx.y;
  const int b = bh >> 3, h = bh & 7;
  const int q0 = blockIdx.x * 64;
  const int tid = threadIdx.x, lane = tid & 63, w = tid >> 6;
  const char* kh = (const char*)(kb + ((long long)bh << 16));
  const char* vh = (const char*)(vt + ((long long)bh << 16));

  auto stageKV = [&](int buf, int t) {
    int k0 = t * 128;
#pragma unroll
    for (int i = 0; i < 4; i++) {
      int c = tid + i * 256;
      int row = c >> 3, cb = (c & 7) << 4;
      int cl = cb ^ ((row & 7) << 4);
      gload_lds16(kh + (long long)(k0 + row) * 128 + cl, (char*)lK + buf * 16384 + c * 16);
    }
#pragma unroll
    for (int i = 0; i < 4; i++) {
      int c = tid + i * 256;
      int row = c >> 4, cb = (c & 15) << 4;
      int cl = cb ^ ((row & 7) << 4);
      gload_lds16(vh + (long long)row * 2048 + (long long)k0 * 2 + cl, (char*)lV + buf * 16384 + c * 16);
    }
  };

  bf16x8 qa[2];
  {
    const __bf16* qrow = qb + ((long long)bh << 16)
                       + (long long)(q0 + w * 16 + (lane & 15)) * 64 + (lane >> 4) * 8;
    qa[0] = *(const bf16x8*)(qrow);
    qa[1] = *(const bf16x8*)(qrow + 32);
  }
  f32x4 oacc[4] = {};
  float m[4], l[4];
#pragma unroll
  for (int r = 0; r < 4; r++) { m[r] = -3e38f; l[r] = 0.f; }

  const int nt = CAUSAL ? (blockIdx.x / 2 + 1) : 8;
  char* lPw = (char*)lP + w * 4096;
  stageKV(0, 0);

  for (int t = 0; t < nt; t++) {
    const int k0 = t * 128;
    __syncthreads();
    if (t + 1 < nt) stageKV((t + 1) & 1, t + 1);
    char* cK = (char*)lK + (t & 1) * 16384;
    char* cV = (char*)lV + (t & 1) * 16384;

    f32x4 sf[8];
#pragma unroll
    for (int f = 0; f < 8; f++) {
      int row = f * 16 + (lane & 15);
      f32x4 s = {};
#pragma unroll
      for (int ks = 0; ks < 2; ks++) {
        int cb = ks * 64 + (lane >> 4) * 16;
        bf16x8 kf = *(const bf16x8*)(cK + row * 128 + (cb ^ ((row & 7) << 4)));
        s = __builtin_amdgcn_mfma_f32_16x16x32_bf16(qa[ks], kf, s, 0, 0, 0);
      }
      sf[f] = s;
    }

    if (!CAUSAL) {
#pragma unroll
      for (int f = 0; f < 8; f++) {
        if (smask[b * 1024 + k0 + f * 16 + (lane & 15)] == 0) {
#pragma unroll
          for (int r = 0; r < 4; r++) sf[f][r] = -1e30f;
        }
      }
    } else if (t == nt - 1) {
#pragma unroll
      for (int f = 0; f < 8; f++) {
        int kc = k0 + f * 16 + (lane & 15);
#pragma unroll
        for (int r = 0; r < 4; r++) {
          int qr = q0 + w * 16 + (lane >> 4) * 4 + r;
          if (kc > qr) sf[f][r] = -1e30f;
        }
      }
    }

    float mt[4], mn[4], cr[4], rs[4];
#pragma unroll
    for (int r = 0; r < 4; r++) {
      float v = sf[0][r];
#pragma unroll
      for (int f = 1; f < 8; f++) v = fmaxf(v, sf[f][r]);
      mt[r] = v;
    }
#pragma unroll
    for (int o = 1; o < 16; o <<= 1)
#pragma unroll
      for (int r = 0; r < 4; r++) mt[r] = fmaxf(mt[r], __shfl_xor(mt[r], o));
#pragma unroll
    for (int r = 0; r < 4; r++) {
      mn[r] = fmaxf(m[r], mt[r]);
      cr[r] = __expf(m[r] - mn[r]);
      m[r]  = mn[r];
      rs[r] = 0.f;
    }
#pragma unroll
    for (int f = 0; f < 8; f++)
#pragma unroll
      for (int r = 0; r < 4; r++) {
        float p = __expf(sf[f][r] - mn[r]);
        sf[f][r] = p;
        rs[r] += p;
      }
#pragma unroll
    for (int o = 1; o < 16; o <<= 1)
#pragma unroll
      for (int r = 0; r < 4; r++) rs[r] += __shfl_xor(rs[r], o);
#pragma unroll
    for (int r = 0; r < 4; r++) l[r] = l[r] * cr[r] + rs[r];
#pragma unroll
    for (int d = 0; d < 4; d++)
#pragma unroll
      for (int r = 0; r < 4; r++) oacc[d][r] *= cr[r];

#pragma unroll
    for (int f = 0; f < 8; f++) {
      int colB = f * 32 + (lane & 15) * 2;
#pragma unroll
      for (int r = 0; r < 4; r++) {
        int row = (lane >> 4) * 4 + r;
        *(__bf16*)(lPw + row * 256 + (colB ^ ((row & 7) << 4))) = (__bf16)sf[f][r];
      }
    }
    asm volatile("s_waitcnt lgkmcnt(0)" ::: "memory");

#pragma unroll
    for (int ks = 0; ks < 4; ks++) {
      int prow = lane & 15;
      int cb = ks * 64 + (lane >> 4) * 16;
      bf16x8 pa = *(const bf16x8*)(lPw + prow * 256 + (cb ^ ((prow & 7) << 4)));
#pragma unroll
      for (int d = 0; d < 4; d++) {
        int vrow = d * 16 + (lane & 15);
        bf16x8 vf = *(const bf16x8*)(cV + vrow * 256 + (cb ^ ((vrow & 7) << 4)));
        oacc[d] = __builtin_amdgcn_mfma_f32_16x16x32_bf16(pa, vf, oacc[d], 0, 0, 0);
      }
    }
  }

  float inv[4];
#pragma unroll
  for (int r = 0; r < 4; r++) inv[r] = 1.f / l[r];
#pragma unroll
  for (int d = 0; d < 4; d++)
#pragma unroll
    for (int r = 0; r < 4; r++) {
      long long row = b * 1024 + q0 + w * 16 + (lane >> 4) * 4 + r;
      Ob[row * 512 + h * 64 + d * 16 + (lane & 15)] = (__bf16)(oacc[d][r] * inv[r]);
    }
}

// ---------------------------------------------------------------------------
__global__ void transpose_w_kernel(const float* __restrict__ W, __bf16* __restrict__ WT,
                                   int K, int N)
{
  __shared__ float t[32][33];
  long long mz = (long long)blockIdx.z * K * N;
  W += mz; WT += mz;
  int n0 = blockIdx.x * 32, k0 = blockIdx.y * 32;
  int tx = threadIdx.x, ty = threadIdx.y;
#pragma unroll
  for (int i = 0; i < 32; i += 8)
    t[ty + i][tx] = W[(long long)(k0 + ty + i) * N + (n0 + tx)];
  __syncthreads();
#pragma unroll
  for (int i = 0; i < 32; i += 8)
    WT[(long long)(n0 + ty + i) * K + (k0 + tx)] = (__bf16)t[tx][ty + i];
}

__global__ void embed_kernel(const float* __restrict__ emb, const int* __restrict__ idx,
                             float* __restrict__ X, __bf16* __restrict__ Xb)
{
  int row = blockIdx.x;
  int s   = row & 1023;
  int tok = idx[row];
  int d0  = threadIdx.x * 4;
  float4 e = *(const float4*)(emb + (long long)tok * 512 + d0);
  const float* ep = (const float*)&e;
  float o[4];
#pragma unroll
  for (int j = 0; j < 4; j++) {
    int d = d0 + j;
    float div = expf((float)(d & ~1) * (-9.210340371976184f / 512.f));
    float ang = (float)s * div;
    float pe  = (d & 1) ? cosf(ang) : sinf(ang);
    o[j] = ep[j] + pe;
  }
  *(float4*)(X + (long long)row * 512 + d0) = *(float4*)o;
  bf16x4 ob;
#pragma unroll
  for (int j = 0; j < 4; j++) ob[j] = (__bf16)o[j];
  *(bf16x4*)(Xb + (long long)row * 512 + d0) = ob;
}

__global__ void ln_kernel(const float* __restrict__ Xin, const float* __restrict__ Rin,
                          const float* __restrict__ g, const float* __restrict__ b,
                          float* __restrict__ Xout, __bf16* __restrict__ Xbout)
{
  int row = blockIdx.x, lane = threadIdx.x;
  long long base = (long long)row * 512 + lane * 8;
  float x[8];
  *(float4*)x       = *(const float4*)(Xin + base);
  *(float4*)(x + 4) = *(const float4*)(Xin + base + 4);
  if (Rin) {
    float4 r0 = *(const float4*)(Rin + base);
    float4 r1 = *(const float4*)(Rin + base + 4);
    x[0] += r0.x; x[1] += r0.y; x[2] += r0.z; x[3] += r0.w;
    x[4] += r1.x; x[5] += r1.y; x[6] += r1.z; x[7] += r1.w;
  }
  float s = 0.f;
#pragma unroll
  for (int i = 0; i < 8; i++) s += x[i];
#pragma unroll
  for (int o = 32; o > 0; o >>= 1) s += __shfl_xor(s, o);
  float mean = s * (1.f / 512.f);
  float v = 0.f;
#pragma unroll
  for (int i = 0; i < 8; i++) { x[i] -= mean; v += x[i] * x[i]; }
#pragma unroll
  for (int o = 32; o > 0; o >>= 1) v += __shfl_xor(v, o);
  float inv = rsqrtf(v * (1.f / 512.f) + 1e-5f);
  int d0 = lane * 8;
  float gg[8], bb[8];
  *(float4*)gg       = *(const float4*)(g + d0);
  *(float4*)(gg + 4) = *(const float4*)(g + d0 + 4);
  *(float4*)bb       = *(const float4*)(b + d0);
  *(float4*)(bb + 4) = *(const float4*)(b + d0 + 4);
  float y[8]; bf16x8 yb;
#pragma unroll
  for (int i = 0; i < 8; i++) {
    y[i] = x[i] * inv * gg[i] + bb[i];
    yb[i] = (__bf16)y[i];
  }
  if (Xout) {
    *(float4*)(Xout + base)     = *(float4*)y;
    *(float4*)(Xout + base + 4) = *(float4*)(y + 4);
  }
  *(bf16x8*)(Xbout + base) = yb;
}

// ---------------------------------------------------------------------------
extern "C" void kernel_launch(void* const* d_in, const int* in_sizes, int n_in,
                              void* d_out, int out_size, void* d_ws, size_t ws_size,
                              hipStream_t stream)
{
  (void)in_sizes; (void)n_in; (void)out_size; (void)ws_size;
  const float* src_emb    = (const float*)d_in[0];
  const float* tgt_emb    = (const float*)d_in[1];
  const float* enc_attn_w = (const float*)d_in[2];
  const float* enc_attn_b = (const float*)d_in[3];
  const float* enc_ffn_w1 = (const float*)d_in[4];
  const float* enc_ffn_b1 = (const float*)d_in[5];
  const float* enc_ffn_w2 = (const float*)d_in[6];
  const float* enc_ffn_b2 = (const float*)d_in[7];
  const float* enc_ln_g   = (const float*)d_in[8];
  const float* enc_ln_b   = (const float*)d_in[9];
  const float* enc_fg     = (const float*)d_in[10];
  const float* enc_fb     = (const float*)d_in[11];
  const float* dec_self_w = (const float*)d_in[12];
  const float* dec_self_b = (const float*)d_in[13];
  const float* dec_src_w  = (const float*)d_in[14];
  const float* dec_src_b  = (const float*)d_in[15];
  const float* dec_ffn_w1 = (const float*)d_in[16];
  const float* dec_ffn_b1 = (const float*)d_in[17];
  const float* dec_ffn_w2 = (const float*)d_in[18];
  const float* dec_ffn_b2 = (const float*)d_in[19];
  const float* dec_ln_g   = (const float*)d_in[20];
  const float* dec_ln_b   = (const float*)d_in[21];
  const float* dec_fg     = (const float*)d_in[22];
  const float* dec_fb     = (const float*)d_in[23];
  const float* gen_w      = (const float*)d_in[24];
  const float* gen_b      = (const float*)d_in[25];
  const int*   src        = (const int*)d_in[26];
  const int*   tgt        = (const int*)d_in[27];
  const int*   src_mask   = (const int*)d_in[28];

  float* out = (float*)d_out;

  // ---- workspace (~130 MB) ----
  char* wp = (char*)d_ws;
  auto alloc = [&](size_t bytes) { void* p = (void*)wp; wp += (bytes + 255) & ~(size_t)255; return p; };
  __bf16* TWea = (__bf16*)alloc(24ull * 262144 * 2);    // enc attn [6][4][512][512]^T
  __bf16* TWe1 = (__bf16*)alloc(6ull * 1048576 * 2);
  __bf16* TWe2 = (__bf16*)alloc(6ull * 1048576 * 2);
  __bf16* TWds = (__bf16*)alloc(24ull * 262144 * 2);
  __bf16* TWdx = (__bf16*)alloc(24ull * 262144 * 2);
  __bf16* TWd1 = (__bf16*)alloc(6ull * 1048576 * 2);
  __bf16* TWd2 = (__bf16*)alloc(6ull * 1048576 * 2);
  float*  X    = (float*) alloc(4096ull * 512 * 4);
  __bf16* Xb   = (__bf16*)alloc(4096ull * 512 * 2);
  __bf16* MEMb = (__bf16*)alloc(4096ull * 512 * 2);
  float*  R    = (float*) alloc(4096ull * 512 * 4);
  __bf16* qb   = (__bf16*)alloc(32ull * 1024 * 64 * 2); // } union with Fb
  __bf16* kb   = (__bf16*)alloc(32ull * 1024 * 64 * 2);
  __bf16* vt   = (__bf16*)alloc(32ull * 1024 * 64 * 2);
  __bf16* Ob   = (__bf16*)alloc(4096ull * 512 * 2);
  __bf16* Fb   = qb;                                    // ffn hidden bf16 [4096][2048]
  __bf16* GENT = TWea;                                  // gen_w^T, after encoder

  // ---- bulk weight transposes ----
  transpose_w_kernel<<<dim3(16, 16, 24), dim3(32, 8), 0, stream>>>(enc_attn_w, TWea, 512, 512);
  transpose_w_kernel<<<dim3(64, 16, 6),  dim3(32, 8), 0, stream>>>(enc_ffn_w1, TWe1, 512, 2048);
  transpose_w_kernel<<<dim3(16, 64, 6),  dim3(32, 8), 0, stream>>>(enc_ffn_w2, TWe2, 2048, 512);
  transpose_w_kernel<<<dim3(16, 16, 24), dim3(32, 8), 0, stream>>>(dec_self_w, TWds, 512, 512);
  transpose_w_kernel<<<dim3(16, 16, 24), dim3(32, 8), 0, stream>>>(dec_src_w,  TWdx, 512, 512);
  transpose_w_kernel<<<dim3(64, 16, 6),  dim3(32, 8), 0, stream>>>(dec_ffn_w1, TWd1, 512, 2048);
  transpose_w_kernel<<<dim3(16, 64, 6),  dim3(32, 8), 0, stream>>>(dec_ffn_w2, TWd2, 2048, 512);

  // attention sublayer: wt = 4 transposed weights [2048][512]; writes R.
  auto attention = [&](const __bf16* wt, const float* bptr, int causal,
                       const __bf16* Aq, const __bf16* Akv) {
    if (Aq == Akv) {
      gemm_kernel<2><<<dim3(32, 24), 256, 0, stream>>>(        // merged QKV N=1536
          Aq, 512, wt, 512, nullptr, 0, bptr, 512, qb, kb, vt, 0);
    } else {
      gemm_kernel<2><<<dim3(32, 8), 256, 0, stream>>>(          // Q only
          Aq, 512, wt, 512, nullptr, 0, bptr, 512, qb, kb, vt, 0);
      gemm_kernel<2><<<dim3(32, 16), 256, 0, stream>>>(         // merged KV N=1024
          Akv, 512, wt + 262144, 512, nullptr, 0, bptr + 512, 512, qb, kb, vt, 1);
    }
    if (causal)
      flash_kernel<1><<<dim3(16, 32), 256, 0, stream>>>(qb, kb, vt, nullptr, Ob);
    else
      flash_kernel<0><<<dim3(16, 32), 256, 0, stream>>>(qb, kb, vt, src_mask, Ob);
    gemm_kernel<0><<<dim3(32, 8), 256, 0, stream>>>(
        Ob, 512, wt + 3 * 262144, 512, R, 512, bptr + 3 * 512, 512,
        nullptr, nullptr, nullptr, 0);
  };

  auto ffn = [&](const __bf16* w1t, const float* b1, const __bf16* w2t, const float* b2) {
    gemm_kernel<1><<<dim3(32, 32), 256, 0, stream>>>(
        Xb, 512, w1t, 512, Fb, 2048, b1, 512, nullptr, nullptr, nullptr, 0);
    gemm_kernel<0><<<dim3(32, 8), 256, 0, stream>>>(
        Fb, 2048, w2t, 2048, R, 512, b2, 2048, nullptr, nullptr, nullptr, 0);
  };

  // ---------------- encoder ----------------
  embed_kernel<<<4096, 128, 0, stream>>>(src_emb, src, X, Xb);
  for (int i = 0; i < 6; i++) {
    attention(TWea + (long long)i * 1048576, enc_attn_b + i * 2048, 0, Xb, Xb);
    ln_kernel<<<4096, 64, 0, stream>>>(X, R, enc_ln_g + i * 1024, enc_ln_b + i * 1024, X, Xb);
    ffn(TWe1 + (long long)i * 1048576, enc_ffn_b1 + i * 2048,
        TWe2 + (long long)i * 1048576, enc_ffn_b2 + i * 512);
    ln_kernel<<<4096, 64, 0, stream>>>(X, R, enc_ln_g + i * 1024 + 512, enc_ln_b + i * 1024 + 512, X, Xb);
  }
  ln_kernel<<<4096, 64, 0, stream>>>(X, nullptr, enc_fg, enc_fb, nullptr, MEMb);

  transpose_w_kernel<<<dim3(1000, 16, 1), dim3(32, 8), 0, stream>>>(gen_w, GENT, 512, 32000);

  // ---------------- decoder ----------------
  embed_kernel<<<4096, 128, 0, stream>>>(tgt_emb, tgt, X, Xb);
  for (int i = 0; i < 6; i++) {
    attention(TWds + (long long)i * 1048576, dec_self_b + i * 2048, 1, Xb, Xb);
    ln_kernel<<<4096, 64, 0, stream>>>(X, R, dec_ln_g + i * 1536, dec_ln_b + i * 1536, X, Xb);

    attention(TWdx + (long long)i * 1048576, dec_src_b + i * 2048, 0, Xb, MEMb);
    ln_kernel<<<4096, 64, 0, stream>>>(X, R, dec_ln_g + i * 1536 + 512, dec_ln_b + i * 1536 + 512, X, Xb);

    ffn(TWd1 + (long long)i * 1048576, dec_ffn_b1 + i * 2048,
        TWd2 + (long long)i * 1048576, dec_ffn_b2 + i * 512);
    ln_kernel<<<4096, 64, 0, stream>>>(X, R, dec_ln_g + i * 1536 + 1024, dec_ln_b + i * 1536 + 1024, X, Xb);
  }
  ln_kernel<<<4096, 64, 0, stream>>>(X, nullptr, dec_fg, dec_fb, nullptr, Xb);

  // ---------------- generator: PIPE3 + T1 + x4 epilogue ----------------
  gemm_gen_kernel<<<16000, 256, 0, stream>>>(
      Xb, 512, GENT, 512, out, 32000, gen_b, 512, 32);
}

// Round 8
// 1962.403 us; speedup vs baseline: 1.0754x; 1.0754x over previous
//
#include <hip/hip_runtime.h>

// ---------------------------------------------------------------------------
// Transformer (enc-dec, D=512, H=8, N=6, DFF=2048, B=4, S=T=1024, V=32000)
// GEMMs: 128x128 PIPE2 (counted vmcnt(8), T2 swizzle) for N>=1024;
//        128x64 PIPE3 (counted vmcnt(6)) for N=512.  Natural grids (no T1).
// Generator adds LDS-transposed dwordx4 store epilogue.
// Fused flash attention; fp32 residual/LN; bulk weight transposes.
// ---------------------------------------------------------------------------

typedef __bf16 bf16x8 __attribute__((ext_vector_type(8)));
typedef __bf16 bf16x4 __attribute__((ext_vector_type(4)));
typedef float  f32x4  __attribute__((ext_vector_type(4)));

__device__ __forceinline__ void gload_lds16(const void* g, void* l) {
  __builtin_amdgcn_global_load_lds((__attribute__((address_space(1))) void*)g,
                                   (__attribute__((address_space(3))) void*)l,
                                   16, 0, 0);
}

__device__ __forceinline__ void hard_barrier() {
  asm volatile("" ::: "memory");
  __builtin_amdgcn_sched_barrier(0);
  __builtin_amdgcn_s_barrier();
  __builtin_amdgcn_sched_barrier(0);
  asm volatile("" ::: "memory");
}

// ---------------------------------------------------------------------------
// PIPE2 128x128 GEMM: C = A[M,K] @ BT[N,K]^T + bias. 256 thr, 4 waves (2x2).
// 2 slots x (A[128][64]+B[128][64]) swizzled; counted vmcnt(8); 2 barriers/tile.
// EPI 0: C fp32. EPI 1: C bf16+ReLU. EPI 2: qkv routing. EPI 3: fp32 via
// LDS-transpose + dwordx4 (generator).
template<int EPI>
__global__ __launch_bounds__(256)
void gemm2_kernel(const __bf16* __restrict__ A, int lda,
                  const __bf16* __restrict__ BT, int ldb,
                  void* __restrict__ Cv, int ldc,
                  const float* __restrict__ bias, int K,
                  __bf16* __restrict__ qb, __bf16* __restrict__ kb,
                  __bf16* __restrict__ vt, int zoff)
{
  constexpr int BM = 128, BN = 128, BK = 64;
  constexpr int WM = 64, WN = 64, FM = 4, FN = 4;
  constexpr int SLOT = 2 * BM * BK;            // elements (A then B)
  __shared__ char ldsraw[69632];               // max(2 slots * 32KB, 128*132*4)
  __bf16* lds = (__bf16*)ldsraw;
  const int tid  = threadIdx.x;
  const int lane = tid & 63, wave = tid >> 6;
  const int wr = wave >> 1, wc = wave & 1;
  const int bm = blockIdx.x * BM, bn = blockIdx.y * BN;

  auto stage = [&](int slot, int kt) {
    const char* Ag = (const char*)A;
    const char* Bg = (const char*)BT;
    char* base = (char*)(lds + slot * SLOT);
    const long long k0b = (long long)kt * (BK * 2);
#pragma unroll
    for (int i = 0; i < 4; i++) {
      int t = tid + i * 256;                   // 0..1023
      int row = t >> 3, cb = (t & 7) << 4;
      int src = cb ^ ((row & 7) << 4);
      gload_lds16(Ag + ((long long)(bm + row) * lda) * 2 + k0b + src, base + t * 16);
    }
#pragma unroll
    for (int i = 0; i < 4; i++) {
      int t = tid + i * 256;
      int row = t >> 3, cb = (t & 7) << 4;
      int src = cb ^ ((row & 7) << 4);
      gload_lds16(Bg + ((long long)(bn + row) * ldb) * 2 + k0b + src,
                  base + BM * BK * 2 + t * 16);
    }
  };

  f32x4 acc[FM][FN] = {};
  const int NT = K / BK;

  stage(0, 0);
  stage(1, 1);

  for (int t = 0; t < NT; t++) {
    if (t < NT - 1) {
      asm volatile("s_waitcnt vmcnt(8)" ::: "memory");   // own tile-t resident
    } else {
      asm volatile("s_waitcnt vmcnt(0)" ::: "memory");
    }
    hard_barrier();
    const char* sA = (const char*)(lds + (t & 1) * SLOT);
    const char* sB = sA + BM * BK * 2;
#pragma unroll
    for (int kk = 0; kk < 2; kk++) {
      const int g = kk * 64 + (lane >> 4) * 16;
      bf16x8 af[FM], bfr[FN];
#pragma unroll
      for (int i = 0; i < FM; i++) {
        int row = wr * WM + i * 16 + (lane & 15);
        af[i] = *(const bf16x8*)(sA + row * 128 + (g ^ ((row & 7) << 4)));
      }
#pragma unroll
      for (int j = 0; j < FN; j++) {
        int row = wc * WN + j * 16 + (lane & 15);
        bfr[j] = *(const bf16x8*)(sB + row * 128 + (g ^ ((row & 7) << 4)));
      }
      __builtin_amdgcn_s_setprio(1);
#pragma unroll
      for (int i = 0; i < FM; i++)
#pragma unroll
        for (int j = 0; j < FN; j++)
          acc[i][j] = __builtin_amdgcn_mfma_f32_16x16x32_bf16(af[i], bfr[j], acc[i][j], 0, 0, 0);
      __builtin_amdgcn_s_setprio(0);
    }
    hard_barrier();                            // slot t&1 released
    if (t + 2 < NT) stage(t & 1, t + 2);       // refill; latency hides under t+1
  }

  if constexpr (EPI == 3) {
    // LDS-transposed epilogue: 128x128 fp32, stride 132 floats, x4 stores.
    __syncthreads();
    float* ct = (float*)ldsraw;                // 128*132*4 = 67584 B
#pragma unroll
    for (int i = 0; i < FM; i++) {
#pragma unroll
      for (int j = 0; j < FN; j++) {
        int lrow = wr * WM + i * 16 + (lane >> 4) * 4;
        int lcol = wc * WN + j * 16 + (lane & 15);
        float bv = bias[bn + lcol];
#pragma unroll
        for (int r = 0; r < 4; r++)
          ct[(lrow + r) * 132 + lcol] = acc[i][j][r] + bv;
      }
    }
    __syncthreads();
    float* C = (float*)Cv;
    // 128 rows x 32 f32x4 = 4096 stores / 256 thr = 16 iterations
#pragma unroll
    for (int it = 0; it < 16; it++) {
      int idx = tid + it * 256;                // 0..4095
      int row = idx >> 5, c4 = (idx & 31) * 4;
      f32x4 v = *(const f32x4*)(ct + row * 132 + c4);
      *(f32x4*)(C + (long long)(bm + row) * ldc + bn + c4) = v;
    }
    return;
  }

#pragma unroll
  for (int i = 0; i < FM; i++) {
#pragma unroll
    for (int j = 0; j < FN; j++) {
      int row0 = bm + wr * WM + i * 16 + (lane >> 4) * 4;
      int col  = bn + wc * WN + j * 16 + (lane & 15);
      float bv = bias ? bias[col] : 0.f;
      if constexpr (EPI == 2) {
        int z = zoff + (col >> 9);
        int cw = col & 511;
        int b = row0 >> 10, s = row0 & 1023;
        int h = cw >> 6, dk = cw & 63;
        long long bh = b * 8 + h;
        if (z == 2) {
          bf16x4 vv;
#pragma unroll
          for (int r = 0; r < 4; r++) vv[r] = (__bf16)(acc[i][j][r] + bv);
          *(bf16x4*)(vt + (bh << 16) + (dk << 10) + s) = vv;
        } else {
          __bf16* dst = (z == 0) ? qb : kb;
          float sc = (z == 0) ? 0.125f : 1.0f;
#pragma unroll
          for (int r = 0; r < 4; r++)
            dst[(bh << 16) + ((long long)(s + r) << 6) + dk] = (__bf16)((acc[i][j][r] + bv) * sc);
        }
      } else if constexpr (EPI == 1) {
        __bf16* C = (__bf16*)Cv;
#pragma unroll
        for (int r = 0; r < 4; r++)
          C[(long long)(row0 + r) * ldc + col] = (__bf16)fmaxf(acc[i][j][r] + bv, 0.f);
      } else {
        float* C = (float*)Cv;
#pragma unroll
        for (int r = 0; r < 4; r++)
          C[(long long)(row0 + r) * ldc + col] = acc[i][j][r] + bv;
      }
    }
  }
}

// ---------------------------------------------------------------------------
// PIPE3 128x64 GEMM (proven r5 kernel): for N=512 call sites.
// EPI 0: C fp32. EPI 2: qkv routing.
template<int EPI>
__global__ __launch_bounds__(256)
void gemm_kernel(const __bf16* __restrict__ A, int lda,
                 const __bf16* __restrict__ BT, int ldb,
                 void* __restrict__ Cv, int ldc,
                 const float* __restrict__ bias, int K,
                 __bf16* __restrict__ qb, __bf16* __restrict__ kb,
                 __bf16* __restrict__ vt, int zoff)
{
  constexpr int BM = 128, BN = 64, BK = 64;
  constexpr int WM = 64, WN = 32, FM = 4, FN = 2;
  constexpr int LA = (BM * BK) / 2048;
  constexpr int LB = (BN * BK) / 2048;
  constexpr int SLOT = (BM + BN) * BK;
  __shared__ __bf16 lds[3 * SLOT];             // 72 KB
  const int tid  = threadIdx.x;
  const int lane = tid & 63, wave = tid >> 6;
  const int wr = wave >> 1, wc = wave & 1;
  const int bm = blockIdx.x * BM, bn = blockIdx.y * BN;

  auto stage = [&](int slot, int kt) {
    const char* Ag = (const char*)A;
    const char* Bg = (const char*)BT;
    char* base = (char*)(lds + slot * SLOT);
    const long long k0b = (long long)kt * (BK * 2);
#pragma unroll
    for (int i = 0; i < LA; i++) {
      int t = tid + i * 256;
      int row = t >> 3, cb = (t & 7) << 4;
      int src = cb ^ ((row & 7) << 4);
      gload_lds16(Ag + ((long long)(bm + row) * lda) * 2 + k0b + src, base + t * 16);
    }
#pragma unroll
    for (int i = 0; i < LB; i++) {
      int t = tid + i * 256;
      int row = t >> 3, cb = (t & 7) << 4;
      int src = cb ^ ((row & 7) << 4);
      gload_lds16(Bg + ((long long)(bn + row) * ldb) * 2 + k0b + src,
                  base + BM * BK * 2 + t * 16);
    }
  };

  f32x4 acc[FM][FN] = {};
  const int NT = K / BK;

  stage(0, 0);
  stage(1, 1);

  for (int t = 0; t < NT; t++) {
    if (t < NT - 1) {
      asm volatile("s_waitcnt vmcnt(6)" ::: "memory");
    } else {
      asm volatile("s_waitcnt vmcnt(0)" ::: "memory");
    }
    hard_barrier();
    if (t + 2 < NT) stage((t + 2) % 3, t + 2);
    const char* sA = (const char*)(lds + (t % 3) * SLOT);
    const char* sB = sA + BM * BK * 2;
#pragma unroll
    for (int kk = 0; kk < 2; kk++) {
      const int g = kk * 64 + (lane >> 4) * 16;
      bf16x8 af[FM], bfr[FN];
#pragma unroll
      for (int i = 0; i < FM; i++) {
        int row = wr * WM + i * 16 + (lane & 15);
        af[i] = *(const bf16x8*)(sA + row * 128 + (g ^ ((row & 7) << 4)));
      }
#pragma unroll
      for (int j = 0; j < FN; j++) {
        int row = wc * WN + j * 16 + (lane & 15);
        bfr[j] = *(const bf16x8*)(sB + row * 128 + (g ^ ((row & 7) << 4)));
      }
      __builtin_amdgcn_s_setprio(1);
#pragma unroll
      for (int i = 0; i < FM; i++)
#pragma unroll
        for (int j = 0; j < FN; j++)
          acc[i][j] = __builtin_amdgcn_mfma_f32_16x16x32_bf16(af[i], bfr[j], acc[i][j], 0, 0, 0);
      __builtin_amdgcn_s_setprio(0);
    }
  }

#pragma unroll
  for (int i = 0; i < FM; i++) {
#pragma unroll
    for (int j = 0; j < FN; j++) {
      int row0 = bm + wr * WM + i * 16 + (lane >> 4) * 4;
      int col  = bn + wc * WN + j * 16 + (lane & 15);
      float bv = bias ? bias[col] : 0.f;
      if constexpr (EPI == 2) {
        int z = zoff + (col >> 9);
        int cw = col & 511;
        int b = row0 >> 10, s = row0 & 1023;
        int h = cw >> 6, dk = cw & 63;
        long long bh = b * 8 + h;
        if (z == 2) {
          bf16x4 vv;
#pragma unroll
          for (int r = 0; r < 4; r++) vv[r] = (__bf16)(acc[i][j][r] + bv);
          *(bf16x4*)(vt + (bh << 16) + (dk << 10) + s) = vv;
        } else {
          __bf16* dst = (z == 0) ? qb : kb;
          float sc = (z == 0) ? 0.125f : 1.0f;
#pragma unroll
          for (int r = 0; r < 4; r++)
            dst[(bh << 16) + ((long long)(s + r) << 6) + dk] = (__bf16)((acc[i][j][r] + bv) * sc);
        }
      } else {
        float* C = (float*)Cv;
#pragma unroll
        for (int r = 0; r < 4; r++)
          C[(long long)(row0 + r) * ldc + col] = acc[i][j][r] + bv;
      }
    }
  }
}

// ---------------------------------------------------------------------------
// Flash attention (unchanged): per block one (bh, 64-row q-tile).
template<int CAUSAL>
__global__ __launch_bounds__(256)
void flash_kernel(const __bf16* __restrict__ qb, const __bf16* __restrict__ kb,
                  const __bf16* __restrict__ vt, const int* __restrict__ smask,
                  __bf16* __restrict__ Ob)
{
  __shared__ __bf16 lK[2 * 128 * 64];
  __shared__ __bf16 lV[2 * 64 * 128];
  __shared__ __bf16 lP[4][16 * 128];
  const int bh = blockIdx.y;
  const int b = bh >> 3, h = bh & 7;
  const int q0 = blockIdx.x * 64;
  const int tid = threadIdx.x, lane = tid & 63, w = tid >> 6;
  const char* kh = (const char*)(kb + ((long long)bh << 16));
  const char* vh = (const char*)(vt + ((long long)bh << 16));

  auto stageKV = [&](int buf, int t) {
    int k0 = t * 128;
#pragma unroll
    for (int i = 0; i < 4; i++) {
      int c = tid + i * 256;
      int row = c >> 3, cb = (c & 7) << 4;
      int cl = cb ^ ((row & 7) << 4);
      gload_lds16(kh + (long long)(k0 + row) * 128 + cl, (char*)lK + buf * 16384 + c * 16);
    }
#pragma unroll
    for (int i = 0; i < 4; i++) {
      int c = tid + i * 256;
      int row = c >> 4, cb = (c & 15) << 4;
      int cl = cb ^ ((row & 7) << 4);
      gload_lds16(vh + (long long)row * 2048 + (long long)k0 * 2 + cl, (char*)lV + buf * 16384 + c * 16);
    }
  };

  bf16x8 qa[2];
  {
    const __bf16* qrow = qb + ((long long)bh << 16)
                       + (long long)(q0 + w * 16 + (lane & 15)) * 64 + (lane >> 4) * 8;
    qa[0] = *(const bf16x8*)(qrow);
    qa[1] = *(const bf16x8*)(qrow + 32);
  }
  f32x4 oacc[4] = {};
  float m[4], l[4];
#pragma unroll
  for (int r = 0; r < 4; r++) { m[r] = -3e38f; l[r] = 0.f; }

  const int nt = CAUSAL ? (blockIdx.x / 2 + 1) : 8;
  char* lPw = (char*)lP + w * 4096;
  stageKV(0, 0);

  for (int t = 0; t < nt; t++) {
    const int k0 = t * 128;
    __syncthreads();
    if (t + 1 < nt) stageKV((t + 1) & 1, t + 1);
    char* cK = (char*)lK + (t & 1) * 16384;
    char* cV = (char*)lV + (t & 1) * 16384;

    f32x4 sf[8];
#pragma unroll
    for (int f = 0; f < 8; f++) {
      int row = f * 16 + (lane & 15);
      f32x4 s = {};
#pragma unroll
      for (int ks = 0; ks < 2; ks++) {
        int cb = ks * 64 + (lane >> 4) * 16;
        bf16x8 kf = *(const bf16x8*)(cK + row * 128 + (cb ^ ((row & 7) << 4)));
        s = __builtin_amdgcn_mfma_f32_16x16x32_bf16(qa[ks], kf, s, 0, 0, 0);
      }
      sf[f] = s;
    }

    if (!CAUSAL) {
#pragma unroll
      for (int f = 0; f < 8; f++) {
        if (smask[b * 1024 + k0 + f * 16 + (lane & 15)] == 0) {
#pragma unroll
          for (int r = 0; r < 4; r++) sf[f][r] = -1e30f;
        }
      }
    } else if (t == nt - 1) {
#pragma unroll
      for (int f = 0; f < 8; f++) {
        int kc = k0 + f * 16 + (lane & 15);
#pragma unroll
        for (int r = 0; r < 4; r++) {
          int qr = q0 + w * 16 + (lane >> 4) * 4 + r;
          if (kc > qr) sf[f][r] = -1e30f;
        }
      }
    }

    float mt[4], mn[4], cr[4], rs[4];
#pragma unroll
    for (int r = 0; r < 4; r++) {
      float v = sf[0][r];
#pragma unroll
      for (int f = 1; f < 8; f++) v = fmaxf(v, sf[f][r]);
      mt[r] = v;
    }
#pragma unroll
    for (int o = 1; o < 16; o <<= 1)
#pragma unroll
      for (int r = 0; r < 4; r++) mt[r] = fmaxf(mt[r], __shfl_xor(mt[r], o));
#pragma unroll
    for (int r = 0; r < 4; r++) {
      mn[r] = fmaxf(m[r], mt[r]);
      cr[r] = __expf(m[r] - mn[r]);
      m[r]  = mn[r];
      rs[r] = 0.f;
    }
#pragma unroll
    for (int f = 0; f < 8; f++)
#pragma unroll
      for (int r = 0; r < 4; r++) {
        float p = __expf(sf[f][r] - mn[r]);
        sf[f][r] = p;
        rs[r] += p;
      }
#pragma unroll
    for (int o = 1; o < 16; o <<= 1)
#pragma unroll
      for (int r = 0; r < 4; r++) rs[r] += __shfl_xor(rs[r], o);
#pragma unroll
    for (int r = 0; r < 4; r++) l[r] = l[r] * cr[r] + rs[r];
#pragma unroll
    for (int d = 0; d < 4; d++)
#pragma unroll
      for (int r = 0; r < 4; r++) oacc[d][r] *= cr[r];

#pragma unroll
    for (int f = 0; f < 8; f++) {
      int colB = f * 32 + (lane & 15) * 2;
#pragma unroll
      for (int r = 0; r < 4; r++) {
        int row = (lane >> 4) * 4 + r;
        *(__bf16*)(lPw + row * 256 + (colB ^ ((row & 7) << 4))) = (__bf16)sf[f][r];
      }
    }
    asm volatile("s_waitcnt lgkmcnt(0)" ::: "memory");

#pragma unroll
    for (int ks = 0; ks < 4; ks++) {
      int prow = lane & 15;
      int cb = ks * 64 + (lane >> 4) * 16;
      bf16x8 pa = *(const bf16x8*)(lPw + prow * 256 + (cb ^ ((prow & 7) << 4)));
#pragma unroll
      for (int d = 0; d < 4; d++) {
        int vrow = d * 16 + (lane & 15);
        bf16x8 vf = *(const bf16x8*)(cV + vrow * 256 + (cb ^ ((vrow & 7) << 4)));
        oacc[d] = __builtin_amdgcn_mfma_f32_16x16x32_bf16(pa, vf, oacc[d], 0, 0, 0);
      }
    }
  }

  float inv[4];
#pragma unroll
  for (int r = 0; r < 4; r++) inv[r] = 1.f / l[r];
#pragma unroll
  for (int d = 0; d < 4; d++)
#pragma unroll
    for (int r = 0; r < 4; r++) {
      long long row = b * 1024 + q0 + w * 16 + (lane >> 4) * 4 + r;
      Ob[row * 512 + h * 64 + d * 16 + (lane & 15)] = (__bf16)(oacc[d][r] * inv[r]);
    }
}

// ---------------------------------------------------------------------------
__global__ void transpose_w_kernel(const float* __restrict__ W, __bf16* __restrict__ WT,
                                   int K, int N)
{
  __shared__ float t[32][33];
  long long mz = (long long)blockIdx.z * K * N;
  W += mz; WT += mz;
  int n0 = blockIdx.x * 32, k0 = blockIdx.y * 32;
  int tx = threadIdx.x, ty = threadIdx.y;
#pragma unroll
  for (int i = 0; i < 32; i += 8)
    t[ty + i][tx] = W[(long long)(k0 + ty + i) * N + (n0 + tx)];
  __syncthreads();
#pragma unroll
  for (int i = 0; i < 32; i += 8)
    WT[(long long)(n0 + ty + i) * K + (k0 + tx)] = (__bf16)t[tx][ty + i];
}

__global__ void embed_kernel(const float* __restrict__ emb, const int* __restrict__ idx,
                             float* __restrict__ X, __bf16* __restrict__ Xb)
{
  int row = blockIdx.x;
  int s   = row & 1023;
  int tok = idx[row];
  int d0  = threadIdx.x * 4;
  float4 e = *(const float4*)(emb + (long long)tok * 512 + d0);
  const float* ep = (const float*)&e;
  float o[4];
#pragma unroll
  for (int j = 0; j < 4; j++) {
    int d = d0 + j;
    float div = expf((float)(d & ~1) * (-9.210340371976184f / 512.f));
    float ang = (float)s * div;
    float pe  = (d & 1) ? cosf(ang) : sinf(ang);
    o[j] = ep[j] + pe;
  }
  *(float4*)(X + (long long)row * 512 + d0) = *(float4*)o;
  bf16x4 ob;
#pragma unroll
  for (int j = 0; j < 4; j++) ob[j] = (__bf16)o[j];
  *(bf16x4*)(Xb + (long long)row * 512 + d0) = ob;
}

__global__ void ln_kernel(const float* __restrict__ Xin, const float* __restrict__ Rin,
                          const float* __restrict__ g, const float* __restrict__ b,
                          float* __restrict__ Xout, __bf16* __restrict__ Xbout)
{
  int row = blockIdx.x, lane = threadIdx.x;
  long long base = (long long)row * 512 + lane * 8;
  float x[8];
  *(float4*)x       = *(const float4*)(Xin + base);
  *(float4*)(x + 4) = *(const float4*)(Xin + base + 4);
  if (Rin) {
    float4 r0 = *(const float4*)(Rin + base);
    float4 r1 = *(const float4*)(Rin + base + 4);
    x[0] += r0.x; x[1] += r0.y; x[2] += r0.z; x[3] += r0.w;
    x[4] += r1.x; x[5] += r1.y; x[6] += r1.z; x[7] += r1.w;
  }
  float s = 0.f;
#pragma unroll
  for (int i = 0; i < 8; i++) s += x[i];
#pragma unroll
  for (int o = 32; o > 0; o >>= 1) s += __shfl_xor(s, o);
  float mean = s * (1.f / 512.f);
  float v = 0.f;
#pragma unroll
  for (int i = 0; i < 8; i++) { x[i] -= mean; v += x[i] * x[i]; }
#pragma unroll
  for (int o = 32; o > 0; o >>= 1) v += __shfl_xor(v, o);
  float inv = rsqrtf(v * (1.f / 512.f) + 1e-5f);
  int d0 = lane * 8;
  float gg[8], bb[8];
  *(float4*)gg       = *(const float4*)(g + d0);
  *(float4*)(gg + 4) = *(const float4*)(g + d0 + 4);
  *(float4*)bb       = *(const float4*)(b + d0);
  *(float4*)(bb + 4) = *(const float4*)(b + d0 + 4);
  float y[8]; bf16x8 yb;
#pragma unroll
  for (int i = 0; i < 8; i++) {
    y[i] = x[i] * inv * gg[i] + bb[i];
    yb[i] = (__bf16)y[i];
  }
  if (Xout) {
    *(float4*)(Xout + base)     = *(float4*)y;
    *(float4*)(Xout + base + 4) = *(float4*)(y + 4);
  }
  *(bf16x8*)(Xbout + base) = yb;
}

// ---------------------------------------------------------------------------
extern "C" void kernel_launch(void* const* d_in, const int* in_sizes, int n_in,
                              void* d_out, int out_size, void* d_ws, size_t ws_size,
                              hipStream_t stream)
{
  (void)in_sizes; (void)n_in; (void)out_size; (void)ws_size;
  const float* src_emb    = (const float*)d_in[0];
  const float* tgt_emb    = (const float*)d_in[1];
  const float* enc_attn_w = (const float*)d_in[2];
  const float* enc_attn_b = (const float*)d_in[3];
  const float* enc_ffn_w1 = (const float*)d_in[4];
  const float* enc_ffn_b1 = (const float*)d_in[5];
  const float* enc_ffn_w2 = (const float*)d_in[6];
  const float* enc_ffn_b2 = (const float*)d_in[7];
  const float* enc_ln_g   = (const float*)d_in[8];
  const float* enc_ln_b   = (const float*)d_in[9];
  const float* enc_fg     = (const float*)d_in[10];
  const float* enc_fb     = (const float*)d_in[11];
  const float* dec_self_w = (const float*)d_in[12];
  const float* dec_self_b = (const float*)d_in[13];
  const float* dec_src_w  = (const float*)d_in[14];
  const float* dec_src_b  = (const float*)d_in[15];
  const float* dec_ffn_w1 = (const float*)d_in[16];
  const float* dec_ffn_b1 = (const float*)d_in[17];
  const float* dec_ffn_w2 = (const float*)d_in[18];
  const float* dec_ffn_b2 = (const float*)d_in[19];
  const float* dec_ln_g   = (const float*)d_in[20];
  const float* dec_ln_b   = (const float*)d_in[21];
  const float* dec_fg     = (const float*)d_in[22];
  const float* dec_fb     = (const float*)d_in[23];
  const float* gen_w      = (const float*)d_in[24];
  const float* gen_b      = (const float*)d_in[25];
  const int*   src        = (const int*)d_in[26];
  const int*   tgt        = (const int*)d_in[27];
  const int*   src_mask   = (const int*)d_in[28];

  float* out = (float*)d_out;

  // ---- workspace (~130 MB) ----
  char* wp = (char*)d_ws;
  auto alloc = [&](size_t bytes) { void* p = (void*)wp; wp += (bytes + 255) & ~(size_t)255; return p; };
  __bf16* TWea = (__bf16*)alloc(24ull * 262144 * 2);    // enc attn [6][4][512][512]^T
  __bf16* TWe1 = (__bf16*)alloc(6ull * 1048576 * 2);
  __bf16* TWe2 = (__bf16*)alloc(6ull * 1048576 * 2);
  __bf16* TWds = (__bf16*)alloc(24ull * 262144 * 2);
  __bf16* TWdx = (__bf16*)alloc(24ull * 262144 * 2);
  __bf16* TWd1 = (__bf16*)alloc(6ull * 1048576 * 2);
  __bf16* TWd2 = (__bf16*)alloc(6ull * 1048576 * 2);
  float*  X    = (float*) alloc(4096ull * 512 * 4);
  __bf16* Xb   = (__bf16*)alloc(4096ull * 512 * 2);
  __bf16* MEMb = (__bf16*)alloc(4096ull * 512 * 2);
  float*  R    = (float*) alloc(4096ull * 512 * 4);
  __bf16* qb   = (__bf16*)alloc(32ull * 1024 * 64 * 2); // } union with Fb
  __bf16* kb   = (__bf16*)alloc(32ull * 1024 * 64 * 2);
  __bf16* vt   = (__bf16*)alloc(32ull * 1024 * 64 * 2);
  __bf16* Ob   = (__bf16*)alloc(4096ull * 512 * 2);
  __bf16* Fb   = qb;                                    // ffn hidden bf16 [4096][2048]
  __bf16* GENT = TWea;                                  // gen_w^T, after encoder

  // ---- bulk weight transposes ----
  transpose_w_kernel<<<dim3(16, 16, 24), dim3(32, 8), 0, stream>>>(enc_attn_w, TWea, 512, 512);
  transpose_w_kernel<<<dim3(64, 16, 6),  dim3(32, 8), 0, stream>>>(enc_ffn_w1, TWe1, 512, 2048);
  transpose_w_kernel<<<dim3(16, 64, 6),  dim3(32, 8), 0, stream>>>(enc_ffn_w2, TWe2, 2048, 512);
  transpose_w_kernel<<<dim3(16, 16, 24), dim3(32, 8), 0, stream>>>(dec_self_w, TWds, 512, 512);
  transpose_w_kernel<<<dim3(16, 16, 24), dim3(32, 8), 0, stream>>>(dec_src_w,  TWdx, 512, 512);
  transpose_w_kernel<<<dim3(64, 16, 6),  dim3(32, 8), 0, stream>>>(dec_ffn_w1, TWd1, 512, 2048);
  transpose_w_kernel<<<dim3(16, 64, 6),  dim3(32, 8), 0, stream>>>(dec_ffn_w2, TWd2, 2048, 512);

  // attention sublayer: wt = 4 transposed weights [2048][512]; writes R.
  auto attention = [&](const __bf16* wt, const float* bptr, int causal,
                       const __bf16* Aq, const __bf16* Akv) {
    if (Aq == Akv) {
      gemm2_kernel<2><<<dim3(32, 12), 256, 0, stream>>>(       // merged QKV N=1536
          Aq, 512, wt, 512, nullptr, 0, bptr, 512, qb, kb, vt, 0);
    } else {
      gemm_kernel<2><<<dim3(32, 8), 256, 0, stream>>>(          // Q only N=512
          Aq, 512, wt, 512, nullptr, 0, bptr, 512, qb, kb, vt, 0);
      gemm2_kernel<2><<<dim3(32, 8), 256, 0, stream>>>(         // merged KV N=1024
          Akv, 512, wt + 262144, 512, nullptr, 0, bptr + 512, 512, qb, kb, vt, 1);
    }
    if (causal)
      flash_kernel<1><<<dim3(16, 32), 256, 0, stream>>>(qb, kb, vt, nullptr, Ob);
    else
      flash_kernel<0><<<dim3(16, 32), 256, 0, stream>>>(qb, kb, vt, src_mask, Ob);
    gemm_kernel<0><<<dim3(32, 8), 256, 0, stream>>>(
        Ob, 512, wt + 3 * 262144, 512, R, 512, bptr + 3 * 512, 512,
        nullptr, nullptr, nullptr, 0);
  };

  auto ffn = [&](const __bf16* w1t, const float* b1, const __bf16* w2t, const float* b2) {
    gemm2_kernel<1><<<dim3(32, 16), 256, 0, stream>>>(
        Xb, 512, w1t, 512, Fb, 2048, b1, 512, nullptr, nullptr, nullptr, 0);
    gemm_kernel<0><<<dim3(32, 8), 256, 0, stream>>>(
        Fb, 2048, w2t, 2048, R, 512, b2, 2048, nullptr, nullptr, nullptr, 0);
  };

  // ---------------- encoder ----------------
  embed_kernel<<<4096, 128, 0, stream>>>(src_emb, src, X, Xb);
  for (int i = 0; i < 6; i++) {
    attention(TWea + (long long)i * 1048576, enc_attn_b + i * 2048, 0, Xb, Xb);
    ln_kernel<<<4096, 64, 0, stream>>>(X, R, enc_ln_g + i * 1024, enc_ln_b + i * 1024, X, Xb);
    ffn(TWe1 + (long long)i * 1048576, enc_ffn_b1 + i * 2048,
        TWe2 + (long long)i * 1048576, enc_ffn_b2 + i * 512);
    ln_kernel<<<4096, 64, 0, stream>>>(X, R, enc_ln_g + i * 1024 + 512, enc_ln_b + i * 1024 + 512, X, Xb);
  }
  ln_kernel<<<4096, 64, 0, stream>>>(X, nullptr, enc_fg, enc_fb, nullptr, MEMb);

  transpose_w_kernel<<<dim3(1000, 16, 1), dim3(32, 8), 0, stream>>>(gen_w, GENT, 512, 32000);

  // ---------------- decoder ----------------
  embed_kernel<<<4096, 128, 0, stream>>>(tgt_emb, tgt, X, Xb);
  for (int i = 0; i < 6; i++) {
    attention(TWds + (long long)i * 1048576, dec_self_b + i * 2048, 1, Xb, Xb);
    ln_kernel<<<4096, 64, 0, stream>>>(X, R, dec_ln_g + i * 1536, dec_ln_b + i * 1536, X, Xb);

    attention(TWdx + (long long)i * 1048576, dec_src_b + i * 2048, 0, Xb, MEMb);
    ln_kernel<<<4096, 64, 0, stream>>>(X, R, dec_ln_g + i * 1536 + 512, dec_ln_b + i * 1536 + 512, X, Xb);

    ffn(TWd1 + (long long)i * 1048576, dec_ffn_b1 + i * 2048,
        TWd2 + (long long)i * 1048576, dec_ffn_b2 + i * 512);
    ln_kernel<<<4096, 64, 0, stream>>>(X, R, dec_ln_g + i * 1536 + 1024, dec_ln_b + i * 1536 + 1024, X, Xb);
  }
  ln_kernel<<<4096, 64, 0, stream>>>(X, nullptr, dec_fg, dec_fb, nullptr, Xb);

  // ---------------- generator: PIPE2 128x128, natural grid ----------------
  gemm2_kernel<3><<<dim3(32, 250), 256, 0, stream>>>(
      Xb, 512, GENT, 512, out, 32000, gen_b, 512, nullptr, nullptr, nullptr, 0);
}

// Round 9
// 1842.921 us; speedup vs baseline: 1.1451x; 1.0648x over previous
//
#include <hip/hip_runtime.h>

// ---------------------------------------------------------------------------
// Transformer (enc-dec, D=512, H=8, N=6, DFF=2048, B=4, S=T=1024, V=32000)
// GEMMs: 128x128 PIPE2 (counted vmcnt(8), T2 swizzle) for N>=1024;
//        128x64 PIPE3 (counted vmcnt(6)) for N=512.
// Flash attention: counted-vmcnt PIPE2 KV staging + defer-max (T13).
// bf16 residual stream (LN reads bf16 base + fp32 branch).
// ---------------------------------------------------------------------------

typedef __bf16 bf16x8 __attribute__((ext_vector_type(8)));
typedef __bf16 bf16x4 __attribute__((ext_vector_type(4)));
typedef float  f32x4  __attribute__((ext_vector_type(4)));

__device__ __forceinline__ void gload_lds16(const void* g, void* l) {
  __builtin_amdgcn_global_load_lds((__attribute__((address_space(1))) void*)g,
                                   (__attribute__((address_space(3))) void*)l,
                                   16, 0, 0);
}

__device__ __forceinline__ void hard_barrier() {
  asm volatile("" ::: "memory");
  __builtin_amdgcn_sched_barrier(0);
  __builtin_amdgcn_s_barrier();
  __builtin_amdgcn_sched_barrier(0);
  asm volatile("" ::: "memory");
}

// ---------------------------------------------------------------------------
// PIPE2 128x128 GEMM. EPI 0: fp32. EPI 1: bf16+ReLU. EPI 2: qkv routing with
// per-column-tile A select (cols<512 -> A, else Akv). EPI 3: fp32 via
// LDS-transpose + dwordx4 (generator).
template<int EPI>
__global__ __launch_bounds__(256)
void gemm2_kernel(const __bf16* __restrict__ A, const __bf16* __restrict__ Akv,
                  int lda,
                  const __bf16* __restrict__ BT, int ldb,
                  void* __restrict__ Cv, int ldc,
                  const float* __restrict__ bias, int K,
                  __bf16* __restrict__ qb, __bf16* __restrict__ kb,
                  __bf16* __restrict__ vt)
{
  constexpr int BM = 128, BN = 128, BK = 64;
  constexpr int WM = 64, WN = 64, FM = 4, FN = 4;
  constexpr int SLOT = 2 * BM * BK;
  __shared__ char ldsraw[69632];
  __bf16* lds = (__bf16*)ldsraw;
  const int tid  = threadIdx.x;
  const int lane = tid & 63, wave = tid >> 6;
  const int wr = wave >> 1, wc = wave & 1;
  const int bm = blockIdx.x * BM, bn = blockIdx.y * BN;
  const __bf16* Ause = (EPI == 2 && blockIdx.y >= 4) ? Akv : A;

  auto stage = [&](int slot, int kt) {
    const char* Ag = (const char*)Ause;
    const char* Bg = (const char*)BT;
    char* base = (char*)(lds + slot * SLOT);
    const long long k0b = (long long)kt * (BK * 2);
#pragma unroll
    for (int i = 0; i < 4; i++) {
      int t = tid + i * 256;
      int row = t >> 3, cb = (t & 7) << 4;
      int src = cb ^ ((row & 7) << 4);
      gload_lds16(Ag + ((long long)(bm + row) * lda) * 2 + k0b + src, base + t * 16);
    }
#pragma unroll
    for (int i = 0; i < 4; i++) {
      int t = tid + i * 256;
      int row = t >> 3, cb = (t & 7) << 4;
      int src = cb ^ ((row & 7) << 4);
      gload_lds16(Bg + ((long long)(bn + row) * ldb) * 2 + k0b + src,
                  base + BM * BK * 2 + t * 16);
    }
  };

  f32x4 acc[FM][FN] = {};
  const int NT = K / BK;

  stage(0, 0);
  stage(1, 1);

  for (int t = 0; t < NT; t++) {
    if (t < NT - 1) {
      asm volatile("s_waitcnt vmcnt(8)" ::: "memory");
    } else {
      asm volatile("s_waitcnt vmcnt(0)" ::: "memory");
    }
    hard_barrier();
    const char* sA = (const char*)(lds + (t & 1) * SLOT);
    const char* sB = sA + BM * BK * 2;
#pragma unroll
    for (int kk = 0; kk < 2; kk++) {
      const int g = kk * 64 + (lane >> 4) * 16;
      bf16x8 af[FM], bfr[FN];
#pragma unroll
      for (int i = 0; i < FM; i++) {
        int row = wr * WM + i * 16 + (lane & 15);
        af[i] = *(const bf16x8*)(sA + row * 128 + (g ^ ((row & 7) << 4)));
      }
#pragma unroll
      for (int j = 0; j < FN; j++) {
        int row = wc * WN + j * 16 + (lane & 15);
        bfr[j] = *(const bf16x8*)(sB + row * 128 + (g ^ ((row & 7) << 4)));
      }
      __builtin_amdgcn_s_setprio(1);
#pragma unroll
      for (int i = 0; i < FM; i++)
#pragma unroll
        for (int j = 0; j < FN; j++)
          acc[i][j] = __builtin_amdgcn_mfma_f32_16x16x32_bf16(af[i], bfr[j], acc[i][j], 0, 0, 0);
      __builtin_amdgcn_s_setprio(0);
    }
    hard_barrier();
    if (t + 2 < NT) stage(t & 1, t + 2);
  }

  if constexpr (EPI == 3) {
    __syncthreads();
    float* ct = (float*)ldsraw;                // 128*132*4 = 67584 B
#pragma unroll
    for (int i = 0; i < FM; i++) {
#pragma unroll
      for (int j = 0; j < FN; j++) {
        int lrow = wr * WM + i * 16 + (lane >> 4) * 4;
        int lcol = wc * WN + j * 16 + (lane & 15);
        float bv = bias[bn + lcol];
#pragma unroll
        for (int r = 0; r < 4; r++)
          ct[(lrow + r) * 132 + lcol] = acc[i][j][r] + bv;
      }
    }
    __syncthreads();
    float* C = (float*)Cv;
#pragma unroll
    for (int it = 0; it < 16; it++) {
      int idx = tid + it * 256;
      int row = idx >> 5, c4 = (idx & 31) * 4;
      f32x4 v = *(const f32x4*)(ct + row * 132 + c4);
      *(f32x4*)(C + (long long)(bm + row) * ldc + bn + c4) = v;
    }
    return;
  }

#pragma unroll
  for (int i = 0; i < FM; i++) {
#pragma unroll
    for (int j = 0; j < FN; j++) {
      int row0 = bm + wr * WM + i * 16 + (lane >> 4) * 4;
      int col  = bn + wc * WN + j * 16 + (lane & 15);
      float bv = bias ? bias[col] : 0.f;
      if constexpr (EPI == 2) {
        int z = col >> 9;
        int cw = col & 511;
        int b = row0 >> 10, s = row0 & 1023;
        int h = cw >> 6, dk = cw & 63;
        long long bh = b * 8 + h;
        if (z == 2) {
          bf16x4 vv;
#pragma unroll
          for (int r = 0; r < 4; r++) vv[r] = (__bf16)(acc[i][j][r] + bv);
          *(bf16x4*)(vt + (bh << 16) + (dk << 10) + s) = vv;
        } else {
          __bf16* dst = (z == 0) ? qb : kb;
          float sc = (z == 0) ? 0.125f : 1.0f;
#pragma unroll
          for (int r = 0; r < 4; r++)
            dst[(bh << 16) + ((long long)(s + r) << 6) + dk] = (__bf16)((acc[i][j][r] + bv) * sc);
        }
      } else if constexpr (EPI == 1) {
        __bf16* C = (__bf16*)Cv;
#pragma unroll
        for (int r = 0; r < 4; r++)
          C[(long long)(row0 + r) * ldc + col] = (__bf16)fmaxf(acc[i][j][r] + bv, 0.f);
      } else {
        float* C = (float*)Cv;
#pragma unroll
        for (int r = 0; r < 4; r++)
          C[(long long)(row0 + r) * ldc + col] = acc[i][j][r] + bv;
      }
    }
  }
}

// ---------------------------------------------------------------------------
// PIPE3 128x64 GEMM: N=512 call sites (O-proj, FFN2). EPI 0: fp32 out.
__global__ __launch_bounds__(256)
void gemm_kernel(const __bf16* __restrict__ A, int lda,
                 const __bf16* __restrict__ BT, int ldb,
                 float* __restrict__ C, int ldc,
                 const float* __restrict__ bias, int K)
{
  constexpr int BM = 128, BN = 64, BK = 64;
  constexpr int WM = 64, WN = 32, FM = 4, FN = 2;
  constexpr int LA = (BM * BK) / 2048;
  constexpr int LB = (BN * BK) / 2048;
  constexpr int SLOT = (BM + BN) * BK;
  __shared__ __bf16 lds[3 * SLOT];
  const int tid  = threadIdx.x;
  const int lane = tid & 63, wave = tid >> 6;
  const int wr = wave >> 1, wc = wave & 1;
  const int bm = blockIdx.x * BM, bn = blockIdx.y * BN;

  auto stage = [&](int slot, int kt) {
    const char* Ag = (const char*)A;
    const char* Bg = (const char*)BT;
    char* base = (char*)(lds + slot * SLOT);
    const long long k0b = (long long)kt * (BK * 2);
#pragma unroll
    for (int i = 0; i < LA; i++) {
      int t = tid + i * 256;
      int row = t >> 3, cb = (t & 7) << 4;
      int src = cb ^ ((row & 7) << 4);
      gload_lds16(Ag + ((long long)(bm + row) * lda) * 2 + k0b + src, base + t * 16);
    }
#pragma unroll
    for (int i = 0; i < LB; i++) {
      int t = tid + i * 256;
      int row = t >> 3, cb = (t & 7) << 4;
      int src = cb ^ ((row & 7) << 4);
      gload_lds16(Bg + ((long long)(bn + row) * ldb) * 2 + k0b + src,
                  base + BM * BK * 2 + t * 16);
    }
  };

  f32x4 acc[FM][FN] = {};
  const int NT = K / BK;

  stage(0, 0);
  stage(1, 1);

  for (int t = 0; t < NT; t++) {
    if (t < NT - 1) {
      asm volatile("s_waitcnt vmcnt(6)" ::: "memory");
    } else {
      asm volatile("s_waitcnt vmcnt(0)" ::: "memory");
    }
    hard_barrier();
    if (t + 2 < NT) stage((t + 2) % 3, t + 2);
    const char* sA = (const char*)(lds + (t % 3) * SLOT);
    const char* sB = sA + BM * BK * 2;
#pragma unroll
    for (int kk = 0; kk < 2; kk++) {
      const int g = kk * 64 + (lane >> 4) * 16;
      bf16x8 af[FM], bfr[FN];
#pragma unroll
      for (int i = 0; i < FM; i++) {
        int row = wr * WM + i * 16 + (lane & 15);
        af[i] = *(const bf16x8*)(sA + row * 128 + (g ^ ((row & 7) << 4)));
      }
#pragma unroll
      for (int j = 0; j < FN; j++) {
        int row = wc * WN + j * 16 + (lane & 15);
        bfr[j] = *(const bf16x8*)(sB + row * 128 + (g ^ ((row & 7) << 4)));
      }
      __builtin_amdgcn_s_setprio(1);
#pragma unroll
      for (int i = 0; i < FM; i++)
#pragma unroll
        for (int j = 0; j < FN; j++)
          acc[i][j] = __builtin_amdgcn_mfma_f32_16x16x32_bf16(af[i], bfr[j], acc[i][j], 0, 0, 0);
      __builtin_amdgcn_s_setprio(0);
    }
  }

#pragma unroll
  for (int i = 0; i < FM; i++) {
#pragma unroll
    for (int j = 0; j < FN; j++) {
      int row0 = bm + wr * WM + i * 16 + (lane >> 4) * 4;
      int col  = bn + wc * WN + j * 16 + (lane & 15);
      float bv = bias ? bias[col] : 0.f;
#pragma unroll
      for (int r = 0; r < 4; r++)
        C[(long long)(row0 + r) * ldc + col] = acc[i][j][r] + bv;
    }
  }
}

// ---------------------------------------------------------------------------
// Flash attention: counted-vmcnt PIPE2 KV staging + defer-max (THR=8).
template<int CAUSAL>
__global__ __launch_bounds__(256)
void flash_kernel(const __bf16* __restrict__ qb, const __bf16* __restrict__ kb,
                  const __bf16* __restrict__ vt, const int* __restrict__ smask,
                  __bf16* __restrict__ Ob)
{
  __shared__ __bf16 lK[2 * 128 * 64];
  __shared__ __bf16 lV[2 * 64 * 128];
  __shared__ __bf16 lP[4][16 * 128];
  const int bh = blockIdx.y;
  const int b = bh >> 3, h = bh & 7;
  const int q0 = blockIdx.x * 64;
  const int tid = threadIdx.x, lane = tid & 63, w = tid >> 6;
  const char* kh = (const char*)(kb + ((long long)bh << 16));
  const char* vh = (const char*)(vt + ((long long)bh << 16));

  auto stageKV = [&](int buf, int t) {
    int k0 = t * 128;
#pragma unroll
    for (int i = 0; i < 4; i++) {
      int c = tid + i * 256;
      int row = c >> 3, cb = (c & 7) << 4;
      int cl = cb ^ ((row & 7) << 4);
      gload_lds16(kh + (long long)(k0 + row) * 128 + cl, (char*)lK + buf * 16384 + c * 16);
    }
#pragma unroll
    for (int i = 0; i < 4; i++) {
      int c = tid + i * 256;
      int row = c >> 4, cb = (c & 15) << 4;
      int cl = cb ^ ((row & 7) << 4);
      gload_lds16(vh + (long long)row * 2048 + (long long)k0 * 2 + cl, (char*)lV + buf * 16384 + c * 16);
    }
  };

  // Q loads issued first: oldest in vmem queue, drained by first counted wait.
  bf16x8 qa[2];
  {
    const __bf16* qrow = qb + ((long long)bh << 16)
                       + (long long)(q0 + w * 16 + (lane & 15)) * 64 + (lane >> 4) * 8;
    qa[0] = *(const bf16x8*)(qrow);
    qa[1] = *(const bf16x8*)(qrow + 32);
  }
  f32x4 oacc[4] = {};
  float m[4], l[4];
#pragma unroll
  for (int r = 0; r < 4; r++) { m[r] = -3e38f; l[r] = 0.f; }

  const int nt = CAUSAL ? (blockIdx.x / 2 + 1) : 8;
  char* lPw = (char*)lP + w * 4096;

  stageKV(0, 0);
  if (nt > 1) stageKV(1, 1);

  for (int t = 0; t < nt; t++) {
    const int k0 = t * 128;
    if (t < nt - 1) {
      asm volatile("s_waitcnt vmcnt(8)" ::: "memory");   // own tile resident
    } else {
      asm volatile("s_waitcnt vmcnt(0)" ::: "memory");
    }
    hard_barrier();
    char* cK = (char*)lK + (t & 1) * 16384;
    char* cV = (char*)lV + (t & 1) * 16384;

    f32x4 sf[8];
#pragma unroll
    for (int f = 0; f < 8; f++) {
      int row = f * 16 + (lane & 15);
      f32x4 s = {};
#pragma unroll
      for (int ks = 0; ks < 2; ks++) {
        int cb = ks * 64 + (lane >> 4) * 16;
        bf16x8 kf = *(const bf16x8*)(cK + row * 128 + (cb ^ ((row & 7) << 4)));
        s = __builtin_amdgcn_mfma_f32_16x16x32_bf16(qa[ks], kf, s, 0, 0, 0);
      }
      sf[f] = s;
    }

    if (!CAUSAL) {
#pragma unroll
      for (int f = 0; f < 8; f++) {
        if (smask[b * 1024 + k0 + f * 16 + (lane & 15)] == 0) {
#pragma unroll
          for (int r = 0; r < 4; r++) sf[f][r] = -1e30f;
        }
      }
    } else if (t == nt - 1) {
#pragma unroll
      for (int f = 0; f < 8; f++) {
        int kc = k0 + f * 16 + (lane & 15);
#pragma unroll
        for (int r = 0; r < 4; r++) {
          int qr = q0 + w * 16 + (lane >> 4) * 4 + r;
          if (kc > qr) sf[f][r] = -1e30f;
        }
      }
    }

    // ---- online softmax with defer-max (THR=8) ----
    float mt[4];
#pragma unroll
    for (int r = 0; r < 4; r++) {
      float v = sf[0][r];
#pragma unroll
      for (int f = 1; f < 8; f++) v = fmaxf(v, sf[f][r]);
      mt[r] = v;
    }
#pragma unroll
    for (int o = 1; o < 16; o <<= 1)
#pragma unroll
      for (int r = 0; r < 4; r++) mt[r] = fmaxf(mt[r], __shfl_xor(mt[r], o));

    bool need = false;
#pragma unroll
    for (int r = 0; r < 4; r++) need = need || (mt[r] > m[r] + 8.f);
    if (__any(need)) {
      float mn[4], cr[4];
#pragma unroll
      for (int r = 0; r < 4; r++) {
        mn[r] = fmaxf(m[r], mt[r]);
        cr[r] = __expf(m[r] - mn[r]);
        m[r]  = mn[r];
        l[r] *= cr[r];
      }
#pragma unroll
      for (int d = 0; d < 4; d++)
#pragma unroll
        for (int r = 0; r < 4; r++) oacc[d][r] *= cr[r];
    }
    float rs[4] = {0.f, 0.f, 0.f, 0.f};
#pragma unroll
    for (int f = 0; f < 8; f++)
#pragma unroll
      for (int r = 0; r < 4; r++) {
        float p = __expf(sf[f][r] - m[r]);
        sf[f][r] = p;
        rs[r] += p;
      }
#pragma unroll
    for (int o = 1; o < 16; o <<= 1)
#pragma unroll
      for (int r = 0; r < 4; r++) rs[r] += __shfl_xor(rs[r], o);
#pragma unroll
    for (int r = 0; r < 4; r++) l[r] += rs[r];

    // ---- P to per-wave swizzled LDS ----
#pragma unroll
    for (int f = 0; f < 8; f++) {
      int colB = f * 32 + (lane & 15) * 2;
#pragma unroll
      for (int r = 0; r < 4; r++) {
        int row = (lane >> 4) * 4 + r;
        *(__bf16*)(lPw + row * 256 + (colB ^ ((row & 7) << 4))) = (__bf16)sf[f][r];
      }
    }
    asm volatile("s_waitcnt lgkmcnt(0)" ::: "memory");

    // ---- O += P @ V ----
#pragma unroll
    for (int ks = 0; ks < 4; ks++) {
      int prow = lane & 15;
      int cb = ks * 64 + (lane >> 4) * 16;
      bf16x8 pa = *(const bf16x8*)(lPw + prow * 256 + (cb ^ ((prow & 7) << 4)));
#pragma unroll
      for (int d = 0; d < 4; d++) {
        int vrow = d * 16 + (lane & 15);
        bf16x8 vf = *(const bf16x8*)(cV + vrow * 256 + (cb ^ ((vrow & 7) << 4)));
        oacc[d] = __builtin_amdgcn_mfma_f32_16x16x32_bf16(pa, vf, oacc[d], 0, 0, 0);
      }
    }
    hard_barrier();                            // buf t&1 released
    if (t + 2 < nt) stageKV(t & 1, t + 2);
  }

  float inv[4];
#pragma unroll
  for (int r = 0; r < 4; r++) inv[r] = 1.f / l[r];
#pragma unroll
  for (int d = 0; d < 4; d++)
#pragma unroll
    for (int r = 0; r < 4; r++) {
      long long row = b * 1024 + q0 + w * 16 + (lane >> 4) * 4 + r;
      Ob[row * 512 + h * 64 + d * 16 + (lane & 15)] = (__bf16)(oacc[d][r] * inv[r]);
    }
}

// ---------------------------------------------------------------------------
__global__ void transpose_w_kernel(const float* __restrict__ W, __bf16* __restrict__ WT,
                                   int K, int N)
{
  __shared__ float t[32][33];
  long long mz = (long long)blockIdx.z * K * N;
  W += mz; WT += mz;
  int n0 = blockIdx.x * 32, k0 = blockIdx.y * 32;
  int tx = threadIdx.x, ty = threadIdx.y;
#pragma unroll
  for (int i = 0; i < 32; i += 8)
    t[ty + i][tx] = W[(long long)(k0 + ty + i) * N + (n0 + tx)];
  __syncthreads();
#pragma unroll
  for (int i = 0; i < 32; i += 8)
    WT[(long long)(n0 + ty + i) * K + (k0 + tx)] = (__bf16)t[tx][ty + i];
}

// x = bf16(emb[idx] + pe). Grid 4096, block 128.
__global__ void embed_kernel(const float* __restrict__ emb, const int* __restrict__ idx,
                             __bf16* __restrict__ Xb)
{
  int row = blockIdx.x;
  int s   = row & 1023;
  int tok = idx[row];
  int d0  = threadIdx.x * 4;
  float4 e = *(const float4*)(emb + (long long)tok * 512 + d0);
  const float* ep = (const float*)&e;
  bf16x4 ob;
#pragma unroll
  for (int j = 0; j < 4; j++) {
    int d = d0 + j;
    float div = expf((float)(d & ~1) * (-9.210340371976184f / 512.f));
    float ang = (float)s * div;
    float pe  = (d & 1) ? cosf(ang) : sinf(ang);
    ob[j] = (__bf16)(ep[j] + pe);
  }
  *(bf16x4*)(Xb + (long long)row * 512 + d0) = ob;
}

// LayerNorm(bf16 base + fp32 branch) * g + b -> bf16. One wave per row.
__global__ void ln_kernel(const __bf16* __restrict__ Xin, const float* __restrict__ Rin,
                          const float* __restrict__ g, const float* __restrict__ b,
                          __bf16* __restrict__ Xbout)
{
  int row = blockIdx.x, lane = threadIdx.x;
  long long base = (long long)row * 512 + lane * 8;
  bf16x8 xv = *(const bf16x8*)(Xin + base);
  float x[8];
#pragma unroll
  for (int i = 0; i < 8; i++) x[i] = (float)xv[i];
  if (Rin) {
    float4 r0 = *(const float4*)(Rin + base);
    float4 r1 = *(const float4*)(Rin + base + 4);
    x[0] += r0.x; x[1] += r0.y; x[2] += r0.z; x[3] += r0.w;
    x[4] += r1.x; x[5] += r1.y; x[6] += r1.z; x[7] += r1.w;
  }
  float s = 0.f;
#pragma unroll
  for (int i = 0; i < 8; i++) s += x[i];
#pragma unroll
  for (int o = 32; o > 0; o >>= 1) s += __shfl_xor(s, o);
  float mean = s * (1.f / 512.f);
  float v = 0.f;
#pragma unroll
  for (int i = 0; i < 8; i++) { x[i] -= mean; v += x[i] * x[i]; }
#pragma unroll
  for (int o = 32; o > 0; o >>= 1) v += __shfl_xor(v, o);
  float inv = rsqrtf(v * (1.f / 512.f) + 1e-5f);
  int d0 = lane * 8;
  float gg[8], bb[8];
  *(float4*)gg       = *(const float4*)(g + d0);
  *(float4*)(gg + 4) = *(const float4*)(g + d0 + 4);
  *(float4*)bb       = *(const float4*)(b + d0);
  *(float4*)(bb + 4) = *(const float4*)(b + d0 + 4);
  bf16x8 yb;
#pragma unroll
  for (int i = 0; i < 8; i++)
    yb[i] = (__bf16)(x[i] * inv * gg[i] + bb[i]);
  *(bf16x8*)(Xbout + base) = yb;
}

// ---------------------------------------------------------------------------
extern "C" void kernel_launch(void* const* d_in, const int* in_sizes, int n_in,
                              void* d_out, int out_size, void* d_ws, size_t ws_size,
                              hipStream_t stream)
{
  (void)in_sizes; (void)n_in; (void)out_size; (void)ws_size;
  const float* src_emb    = (const float*)d_in[0];
  const float* tgt_emb    = (const float*)d_in[1];
  const float* enc_attn_w = (const float*)d_in[2];
  const float* enc_attn_b = (const float*)d_in[3];
  const float* enc_ffn_w1 = (const float*)d_in[4];
  const float* enc_ffn_b1 = (const float*)d_in[5];
  const float* enc_ffn_w2 = (const float*)d_in[6];
  const float* enc_ffn_b2 = (const float*)d_in[7];
  const float* enc_ln_g   = (const float*)d_in[8];
  const float* enc_ln_b   = (const float*)d_in[9];
  const float* enc_fg     = (const float*)d_in[10];
  const float* enc_fb     = (const float*)d_in[11];
  const float* dec_self_w = (const float*)d_in[12];
  const float* dec_self_b = (const float*)d_in[13];
  const float* dec_src_w  = (const float*)d_in[14];
  const float* dec_src_b  = (const float*)d_in[15];
  const float* dec_ffn_w1 = (const float*)d_in[16];
  const float* dec_ffn_b1 = (const float*)d_in[17];
  const float* dec_ffn_w2 = (const float*)d_in[18];
  const float* dec_ffn_b2 = (const float*)d_in[19];
  const float* dec_ln_g   = (const float*)d_in[20];
  const float* dec_ln_b   = (const float*)d_in[21];
  const float* dec_fg     = (const float*)d_in[22];
  const float* dec_fb     = (const float*)d_in[23];
  const float* gen_w      = (const float*)d_in[24];
  const float* gen_b      = (const float*)d_in[25];
  const int*   src        = (const int*)d_in[26];
  const int*   tgt        = (const int*)d_in[27];
  const int*   src_mask   = (const int*)d_in[28];

  float* out = (float*)d_out;

  // ---- workspace ----
  char* wp = (char*)d_ws;
  auto alloc = [&](size_t bytes) { void* p = (void*)wp; wp += (bytes + 255) & ~(size_t)255; return p; };
  __bf16* TWea = (__bf16*)alloc(24ull * 262144 * 2);    // enc attn [6][4][512][512]^T
  __bf16* TWe1 = (__bf16*)alloc(6ull * 1048576 * 2);
  __bf16* TWe2 = (__bf16*)alloc(6ull * 1048576 * 2);
  __bf16* TWds = (__bf16*)alloc(24ull * 262144 * 2);
  __bf16* TWdx = (__bf16*)alloc(24ull * 262144 * 2);
  __bf16* TWd1 = (__bf16*)alloc(6ull * 1048576 * 2);
  __bf16* TWd2 = (__bf16*)alloc(6ull * 1048576 * 2);
  __bf16* Xb   = (__bf16*)alloc(4096ull * 512 * 2);     // bf16 residual stream
  __bf16* MEMb = (__bf16*)alloc(4096ull * 512 * 2);
  float*  R    = (float*) alloc(4096ull * 512 * 4);     // sublayer branch fp32
  __bf16* qb   = (__bf16*)alloc(32ull * 1024 * 64 * 2); // } union with Fb
  __bf16* kb   = (__bf16*)alloc(32ull * 1024 * 64 * 2);
  __bf16* vt   = (__bf16*)alloc(32ull * 1024 * 64 * 2);
  __bf16* Ob   = (__bf16*)alloc(4096ull * 512 * 2);
  __bf16* Fb   = qb;                                    // ffn hidden bf16 [4096][2048]
  __bf16* GENT = TWea;                                  // gen_w^T, after encoder

  // ---- bulk weight transposes ----
  transpose_w_kernel<<<dim3(16, 16, 24), dim3(32, 8), 0, stream>>>(enc_attn_w, TWea, 512, 512);
  transpose_w_kernel<<<dim3(64, 16, 6),  dim3(32, 8), 0, stream>>>(enc_ffn_w1, TWe1, 512, 2048);
  transpose_w_kernel<<<dim3(16, 64, 6),  dim3(32, 8), 0, stream>>>(enc_ffn_w2, TWe2, 2048, 512);
  transpose_w_kernel<<<dim3(16, 16, 24), dim3(32, 8), 0, stream>>>(dec_self_w, TWds, 512, 512);
  transpose_w_kernel<<<dim3(16, 16, 24), dim3(32, 8), 0, stream>>>(dec_src_w,  TWdx, 512, 512);
  transpose_w_kernel<<<dim3(64, 16, 6),  dim3(32, 8), 0, stream>>>(dec_ffn_w1, TWd1, 512, 2048);
  transpose_w_kernel<<<dim3(16, 64, 6),  dim3(32, 8), 0, stream>>>(dec_ffn_w2, TWd2, 2048, 512);

  // attention sublayer: single unified QKV dispatch; writes R.
  auto attention = [&](const __bf16* wt, const float* bptr, int causal,
                       const __bf16* Aq, const __bf16* Akv) {
    gemm2_kernel<2><<<dim3(32, 12), 256, 0, stream>>>(
        Aq, Akv, 512, wt, 512, nullptr, 0, bptr, 512, qb, kb, vt);
    if (causal)
      flash_kernel<1><<<dim3(16, 32), 256, 0, stream>>>(qb, kb, vt, nullptr, Ob);
    else
      flash_kernel<0><<<dim3(16, 32), 256, 0, stream>>>(qb, kb, vt, src_mask, Ob);
    gemm_kernel<<<dim3(32, 8), 256, 0, stream>>>(
        Ob, 512, wt + 3 * 262144, 512, R, 512, bptr + 3 * 512, 512);
  };

  auto ffn = [&](const __bf16* w1t, const float* b1, const __bf16* w2t, const float* b2) {
    gemm2_kernel<1><<<dim3(32, 16), 256, 0, stream>>>(
        Xb, Xb, 512, w1t, 512, Fb, 2048, b1, 512, nullptr, nullptr, nullptr);
    gemm_kernel<<<dim3(32, 8), 256, 0, stream>>>(
        Fb, 2048, w2t, 2048, R, 512, b2, 2048);
  };

  // ---------------- encoder ----------------
  embed_kernel<<<4096, 128, 0, stream>>>(src_emb, src, Xb);
  for (int i = 0; i < 6; i++) {
    attention(TWea + (long long)i * 1048576, enc_attn_b + i * 2048, 0, Xb, Xb);
    ln_kernel<<<4096, 64, 0, stream>>>(Xb, R, enc_ln_g + i * 1024, enc_ln_b + i * 1024, Xb);
    ffn(TWe1 + (long long)i * 1048576, enc_ffn_b1 + i * 2048,
        TWe2 + (long long)i * 1048576, enc_ffn_b2 + i * 512);
    ln_kernel<<<4096, 64, 0, stream>>>(Xb, R, enc_ln_g + i * 1024 + 512, enc_ln_b + i * 1024 + 512, Xb);
  }
  ln_kernel<<<4096, 64, 0, stream>>>(Xb, nullptr, enc_fg, enc_fb, MEMb);

  transpose_w_kernel<<<dim3(1000, 16, 1), dim3(32, 8), 0, stream>>>(gen_w, GENT, 512, 32000);

  // ---------------- decoder ----------------
  embed_kernel<<<4096, 128, 0, stream>>>(tgt_emb, tgt, Xb);
  for (int i = 0; i < 6; i++) {
    attention(TWds + (long long)i * 1048576, dec_self_b + i * 2048, 1, Xb, Xb);
    ln_kernel<<<4096, 64, 0, stream>>>(Xb, R, dec_ln_g + i * 1536, dec_ln_b + i * 1536, Xb);

    attention(TWdx + (long long)i * 1048576, dec_src_b + i * 2048, 0, Xb, MEMb);
    ln_kernel<<<4096, 64, 0, stream>>>(Xb, R, dec_ln_g + i * 1536 + 512, dec_ln_b + i * 1536 + 512, Xb);

    ffn(TWd1 + (long long)i * 1048576, dec_ffn_b1 + i * 2048,
        TWd2 + (long long)i * 1048576, dec_ffn_b2 + i * 512);
    ln_kernel<<<4096, 64, 0, stream>>>(Xb, R, dec_ln_g + i * 1536 + 1024, dec_ln_b + i * 1536 + 1024, Xb);
  }
  ln_kernel<<<4096, 64, 0, stream>>>(Xb, nullptr, dec_fg, dec_fb, Xb);

  // ---------------- generator: PIPE2 128x128 + x4 epilogue ----------------
  gemm2_kernel<3><<<dim3(32, 250), 256, 0, stream>>>(
      Xb, Xb, 512, GENT, 512, out, 32000, gen_b, 512, nullptr, nullptr, nullptr);
}

// Round 10
// 1836.490 us; speedup vs baseline: 1.1491x; 1.0035x over previous
//
#include <hip/hip_runtime.h>

// ---------------------------------------------------------------------------
// Transformer (enc-dec, D=512, H=8, N=6, DFF=2048, B=4, S=T=1024, V=32000)
// GEMMs: 128x128 PIPE2 (counted vmcnt(8), T2 swizzle) for N>=1024;
//        128x64 PIPE3 (counted vmcnt(6)) for N=512.
// Generator: 256x256 8-wave 4-quadrant-phase kernel (m201-style: per-phase
//   barrier + lgkmcnt(0) + setprio, counted vmcnt(8), T2 swizzle, 128KiB LDS).
// Flash attention: counted-vmcnt PIPE2 KV staging + defer-max (T13).
// bf16 residual stream.
// ---------------------------------------------------------------------------

typedef __bf16 bf16x8 __attribute__((ext_vector_type(8)));
typedef __bf16 bf16x4 __attribute__((ext_vector_type(4)));
typedef float  f32x4  __attribute__((ext_vector_type(4)));

__device__ __forceinline__ void gload_lds16(const void* g, void* l) {
  __builtin_amdgcn_global_load_lds((__attribute__((address_space(1))) void*)g,
                                   (__attribute__((address_space(3))) void*)l,
                                   16, 0, 0);
}

__device__ __forceinline__ void hard_barrier() {
  asm volatile("" ::: "memory");
  __builtin_amdgcn_sched_barrier(0);
  __builtin_amdgcn_s_barrier();
  __builtin_amdgcn_sched_barrier(0);
  asm volatile("" ::: "memory");
}

// ---------------------------------------------------------------------------
// Generator GEMM: 256x256 tile, 512 thr / 8 waves (2M x 4N), BK=64.
// 2 LDS slots x (A[256][64] + B[256][64]) bf16, T2-swizzled; counted vmcnt(8);
// per-tile 4 quadrant-phases {ds_read, barrier, lgkmcnt(0), setprio, 16 MFMA}.
// Epilogue: chunked LDS-transpose, dwordx4 stores, +bias.
__global__ __launch_bounds__(512, 2)
void gemm256_kernel(const __bf16* __restrict__ A, int lda,
                    const __bf16* __restrict__ BT, int ldb,
                    float* __restrict__ C, int ldc,
                    const float* __restrict__ bias, int K)
{
  __shared__ char ldsraw[131072];              // 2 slots x 64 KB
  const int tid  = threadIdx.x;
  const int lane = tid & 63, wid = tid >> 6;
  const int wr = wid >> 2, wc = wid & 3;       // 2 x 4 wave grid
  const int bm = blockIdx.x * 256, bn = blockIdx.y * 256;

  // stage full K-tile kt into slot: A 256x64 then B 256x64 (8 insts/thread)
  auto stage = [&](int slot, int kt) {
    const char* Ag = (const char*)A;
    const char* Bg = (const char*)BT;
    char* base = ldsraw + slot * 65536;
    const long long k0b = (long long)kt * 128;
#pragma unroll
    for (int i = 0; i < 4; i++) {
      int t = tid + i * 512;                   // 0..2047
      int row = t >> 3, cb = (t & 7) << 4;
      int src = cb ^ ((row & 7) << 4);         // inverse-swizzled source
      gload_lds16(Ag + ((long long)(bm + row) * lda) * 2 + k0b + src, base + t * 16);
    }
#pragma unroll
    for (int i = 0; i < 4; i++) {
      int t = tid + i * 512;
      int row = t >> 3, cb = (t & 7) << 4;
      int src = cb ^ ((row & 7) << 4);
      gload_lds16(Bg + ((long long)(bn + row) * ldb) * 2 + k0b + src,
                  base + 32768 + t * 16);
    }
  };

  f32x4 acc[8][4] = {};
  const int NT = K / 64;                       // 8 for K=512

  stage(0, 0);
  stage(1, 1);

  for (int kt = 0; kt < NT; kt++) {
    if (kt < NT - 1) {
      asm volatile("s_waitcnt vmcnt(8)" ::: "memory");   // own tile resident
    } else {
      asm volatile("s_waitcnt vmcnt(0)" ::: "memory");
    }
    hard_barrier();
    const char* sA = ldsraw + (kt & 1) * 65536;
    const char* sB = sA + 32768;
#pragma unroll
    for (int q = 0; q < 4; q++) {              // quadrant phases
      const int qr = q >> 1, qc = q & 1;
      bf16x8 af[4][2], bf[2][2];
#pragma unroll
      for (int i = 0; i < 4; i++) {
        int row = wr * 128 + (qr * 4 + i) * 16 + (lane & 15);
#pragma unroll
        for (int kk = 0; kk < 2; kk++) {
          int g = kk * 64 + (lane >> 4) * 16;
          af[i][kk] = *(const bf16x8*)(sA + row * 128 + (g ^ ((row & 7) << 4)));
        }
      }
#pragma unroll
      for (int j = 0; j < 2; j++) {
        int row = wc * 64 + (qc * 2 + j) * 16 + (lane & 15);
#pragma unroll
        for (int kk = 0; kk < 2; kk++) {
          int g = kk * 64 + (lane >> 4) * 16;
          bf[j][kk] = *(const bf16x8*)(sB + row * 128 + (g ^ ((row & 7) << 4)));
        }
      }
      __builtin_amdgcn_s_barrier();            // phase alignment
      asm volatile("s_waitcnt lgkmcnt(0)" ::: "memory");
      __builtin_amdgcn_sched_barrier(0);       // rule #18
      __builtin_amdgcn_s_setprio(1);
#pragma unroll
      for (int kk = 0; kk < 2; kk++)
#pragma unroll
        for (int i = 0; i < 4; i++)
#pragma unroll
          for (int j = 0; j < 2; j++)
            acc[qr * 4 + i][qc * 2 + j] = __builtin_amdgcn_mfma_f32_16x16x32_bf16(
                af[i][kk], bf[j][kk], acc[qr * 4 + i][qc * 2 + j], 0, 0, 0);
      __builtin_amdgcn_s_setprio(0);
    }
    hard_barrier();                            // slot kt&1 fully consumed
    if (kt + 2 < NT) stage(kt & 1, kt + 2);
  }

  // ---- epilogue: 4 chunks of 64 rows; LDS transpose stride 260 fl ----
  float* ct = (float*)ldsraw;                  // 64*260*4 = 66560 B
#pragma unroll
  for (int c = 0; c < 4; c++) {
    __syncthreads();                           // prev chunk read / LDS free
    if (wr == (c >> 1)) {
      const int ib = (c & 1) * 4;
#pragma unroll
      for (int i = 0; i < 4; i++) {
#pragma unroll
        for (int j = 0; j < 4; j++) {
          int lrow = i * 16 + (lane >> 4) * 4;         // 0..63 within chunk
          int lcol = wc * 64 + j * 16 + (lane & 15);   // 0..255
          float bv = bias[bn + lcol];
#pragma unroll
          for (int r = 0; r < 4; r++)
            ct[(lrow + r) * 260 + lcol] = acc[ib + i][j][r] + bv;
        }
      }
    }
    __syncthreads();
    // 64 rows x 64 f32x4 = 4096 stores / 512 thr = 8 iters
#pragma unroll
    for (int it = 0; it < 8; it++) {
      int idx = tid + it * 512;                // 0..4095
      int row = idx >> 6, c4 = (idx & 63) * 4;
      f32x4 v = *(const f32x4*)(ct + row * 260 + c4);
      *(f32x4*)(C + (long long)(bm + c * 64 + row) * ldc + bn + c4) = v;
    }
  }
}

// ---------------------------------------------------------------------------
// PIPE2 128x128 GEMM. EPI 0: fp32. EPI 1: bf16+ReLU. EPI 2: qkv routing with
// per-column-tile A select (cols<512 -> A, else Akv).
template<int EPI>
__global__ __launch_bounds__(256)
void gemm2_kernel(const __bf16* __restrict__ A, const __bf16* __restrict__ Akv,
                  int lda,
                  const __bf16* __restrict__ BT, int ldb,
                  void* __restrict__ Cv, int ldc,
                  const float* __restrict__ bias, int K,
                  __bf16* __restrict__ qb, __bf16* __restrict__ kb,
                  __bf16* __restrict__ vt)
{
  constexpr int BM = 128, BN = 128, BK = 64;
  constexpr int WM = 64, WN = 64, FM = 4, FN = 4;
  constexpr int SLOT = 2 * BM * BK;
  __shared__ char ldsraw[65536];
  __bf16* lds = (__bf16*)ldsraw;
  const int tid  = threadIdx.x;
  const int lane = tid & 63, wave = tid >> 6;
  const int wr = wave >> 1, wc = wave & 1;
  const int bm = blockIdx.x * BM, bn = blockIdx.y * BN;
  const __bf16* Ause = (EPI == 2 && blockIdx.y >= 4) ? Akv : A;

  auto stage = [&](int slot, int kt) {
    const char* Ag = (const char*)Ause;
    const char* Bg = (const char*)BT;
    char* base = (char*)(lds + slot * SLOT);
    const long long k0b = (long long)kt * (BK * 2);
#pragma unroll
    for (int i = 0; i < 4; i++) {
      int t = tid + i * 256;
      int row = t >> 3, cb = (t & 7) << 4;
      int src = cb ^ ((row & 7) << 4);
      gload_lds16(Ag + ((long long)(bm + row) * lda) * 2 + k0b + src, base + t * 16);
    }
#pragma unroll
    for (int i = 0; i < 4; i++) {
      int t = tid + i * 256;
      int row = t >> 3, cb = (t & 7) << 4;
      int src = cb ^ ((row & 7) << 4);
      gload_lds16(Bg + ((long long)(bn + row) * ldb) * 2 + k0b + src,
                  base + BM * BK * 2 + t * 16);
    }
  };

  f32x4 acc[FM][FN] = {};
  const int NT = K / BK;

  stage(0, 0);
  stage(1, 1);

  for (int t = 0; t < NT; t++) {
    if (t < NT - 1) {
      asm volatile("s_waitcnt vmcnt(8)" ::: "memory");
    } else {
      asm volatile("s_waitcnt vmcnt(0)" ::: "memory");
    }
    hard_barrier();
    const char* sA = (const char*)(lds + (t & 1) * SLOT);
    const char* sB = sA + BM * BK * 2;
#pragma unroll
    for (int kk = 0; kk < 2; kk++) {
      const int g = kk * 64 + (lane >> 4) * 16;
      bf16x8 af[FM], bfr[FN];
#pragma unroll
      for (int i = 0; i < FM; i++) {
        int row = wr * WM + i * 16 + (lane & 15);
        af[i] = *(const bf16x8*)(sA + row * 128 + (g ^ ((row & 7) << 4)));
      }
#pragma unroll
      for (int j = 0; j < FN; j++) {
        int row = wc * WN + j * 16 + (lane & 15);
        bfr[j] = *(const bf16x8*)(sB + row * 128 + (g ^ ((row & 7) << 4)));
      }
      __builtin_amdgcn_s_setprio(1);
#pragma unroll
      for (int i = 0; i < FM; i++)
#pragma unroll
        for (int j = 0; j < FN; j++)
          acc[i][j] = __builtin_amdgcn_mfma_f32_16x16x32_bf16(af[i], bfr[j], acc[i][j], 0, 0, 0);
      __builtin_amdgcn_s_setprio(0);
    }
    hard_barrier();
    if (t + 2 < NT) stage(t & 1, t + 2);
  }

#pragma unroll
  for (int i = 0; i < FM; i++) {
#pragma unroll
    for (int j = 0; j < FN; j++) {
      int row0 = bm + wr * WM + i * 16 + (lane >> 4) * 4;
      int col  = bn + wc * WN + j * 16 + (lane & 15);
      float bv = bias ? bias[col] : 0.f;
      if constexpr (EPI == 2) {
        int z = col >> 9;
        int cw = col & 511;
        int b = row0 >> 10, s = row0 & 1023;
        int h = cw >> 6, dk = cw & 63;
        long long bh = b * 8 + h;
        if (z == 2) {
          bf16x4 vv;
#pragma unroll
          for (int r = 0; r < 4; r++) vv[r] = (__bf16)(acc[i][j][r] + bv);
          *(bf16x4*)(vt + (bh << 16) + (dk << 10) + s) = vv;
        } else {
          __bf16* dst = (z == 0) ? qb : kb;
          float sc = (z == 0) ? 0.125f : 1.0f;
#pragma unroll
          for (int r = 0; r < 4; r++)
            dst[(bh << 16) + ((long long)(s + r) << 6) + dk] = (__bf16)((acc[i][j][r] + bv) * sc);
        }
      } else if constexpr (EPI == 1) {
        __bf16* C = (__bf16*)Cv;
#pragma unroll
        for (int r = 0; r < 4; r++)
          C[(long long)(row0 + r) * ldc + col] = (__bf16)fmaxf(acc[i][j][r] + bv, 0.f);
      } else {
        float* C = (float*)Cv;
#pragma unroll
        for (int r = 0; r < 4; r++)
          C[(long long)(row0 + r) * ldc + col] = acc[i][j][r] + bv;
      }
    }
  }
}

// ---------------------------------------------------------------------------
// PIPE3 128x64 GEMM: N=512 call sites (O-proj, FFN2). fp32 out.
__global__ __launch_bounds__(256)
void gemm_kernel(const __bf16* __restrict__ A, int lda,
                 const __bf16* __restrict__ BT, int ldb,
                 float* __restrict__ C, int ldc,
                 const float* __restrict__ bias, int K)
{
  constexpr int BM = 128, BN = 64, BK = 64;
  constexpr int WM = 64, WN = 32, FM = 4, FN = 2;
  constexpr int LA = (BM * BK) / 2048;
  constexpr int LB = (BN * BK) / 2048;
  constexpr int SLOT = (BM + BN) * BK;
  __shared__ __bf16 lds[3 * SLOT];
  const int tid  = threadIdx.x;
  const int lane = tid & 63, wave = tid >> 6;
  const int wr = wave >> 1, wc = wave & 1;
  const int bm = blockIdx.x * BM, bn = blockIdx.y * BN;

  auto stage = [&](int slot, int kt) {
    const char* Ag = (const char*)A;
    const char* Bg = (const char*)BT;
    char* base = (char*)(lds + slot * SLOT);
    const long long k0b = (long long)kt * (BK * 2);
#pragma unroll
    for (int i = 0; i < LA; i++) {
      int t = tid + i * 256;
      int row = t >> 3, cb = (t & 7) << 4;
      int src = cb ^ ((row & 7) << 4);
      gload_lds16(Ag + ((long long)(bm + row) * lda) * 2 + k0b + src, base + t * 16);
    }
#pragma unroll
    for (int i = 0; i < LB; i++) {
      int t = tid + i * 256;
      int row = t >> 3, cb = (t & 7) << 4;
      int src = cb ^ ((row & 7) << 4);
      gload_lds16(Bg + ((long long)(bn + row) * ldb) * 2 + k0b + src,
                  base + BM * BK * 2 + t * 16);
    }
  };

  f32x4 acc[FM][FN] = {};
  const int NT = K / BK;

  stage(0, 0);
  stage(1, 1);

  for (int t = 0; t < NT; t++) {
    if (t < NT - 1) {
      asm volatile("s_waitcnt vmcnt(6)" ::: "memory");
    } else {
      asm volatile("s_waitcnt vmcnt(0)" ::: "memory");
    }
    hard_barrier();
    if (t + 2 < NT) stage((t + 2) % 3, t + 2);
    const char* sA = (const char*)(lds + (t % 3) * SLOT);
    const char* sB = sA + BM * BK * 2;
#pragma unroll
    for (int kk = 0; kk < 2; kk++) {
      const int g = kk * 64 + (lane >> 4) * 16;
      bf16x8 af[FM], bfr[FN];
#pragma unroll
      for (int i = 0; i < FM; i++) {
        int row = wr * WM + i * 16 + (lane & 15);
        af[i] = *(const bf16x8*)(sA + row * 128 + (g ^ ((row & 7) << 4)));
      }
#pragma unroll
      for (int j = 0; j < FN; j++) {
        int row = wc * WN + j * 16 + (lane & 15);
        bfr[j] = *(const bf16x8*)(sB + row * 128 + (g ^ ((row & 7) << 4)));
      }
      __builtin_amdgcn_s_setprio(1);
#pragma unroll
      for (int i = 0; i < FM; i++)
#pragma unroll
        for (int j = 0; j < FN; j++)
          acc[i][j] = __builtin_amdgcn_mfma_f32_16x16x32_bf16(af[i], bfr[j], acc[i][j], 0, 0, 0);
      __builtin_amdgcn_s_setprio(0);
    }
  }

#pragma unroll
  for (int i = 0; i < FM; i++) {
#pragma unroll
    for (int j = 0; j < FN; j++) {
      int row0 = bm + wr * WM + i * 16 + (lane >> 4) * 4;
      int col  = bn + wc * WN + j * 16 + (lane & 15);
      float bv = bias ? bias[col] : 0.f;
#pragma unroll
      for (int r = 0; r < 4; r++)
        C[(long long)(row0 + r) * ldc + col] = acc[i][j][r] + bv;
    }
  }
}

// ---------------------------------------------------------------------------
// Flash attention: counted-vmcnt PIPE2 KV staging + defer-max (THR=8).
template<int CAUSAL>
__global__ __launch_bounds__(256)
void flash_kernel(const __bf16* __restrict__ qb, const __bf16* __restrict__ kb,
                  const __bf16* __restrict__ vt, const int* __restrict__ smask,
                  __bf16* __restrict__ Ob)
{
  __shared__ __bf16 lK[2 * 128 * 64];
  __shared__ __bf16 lV[2 * 64 * 128];
  __shared__ __bf16 lP[4][16 * 128];
  const int bh = blockIdx.y;
  const int b = bh >> 3, h = bh & 7;
  const int q0 = blockIdx.x * 64;
  const int tid = threadIdx.x, lane = tid & 63, w = tid >> 6;
  const char* kh = (const char*)(kb + ((long long)bh << 16));
  const char* vh = (const char*)(vt + ((long long)bh << 16));

  auto stageKV = [&](int buf, int t) {
    int k0 = t * 128;
#pragma unroll
    for (int i = 0; i < 4; i++) {
      int c = tid + i * 256;
      int row = c >> 3, cb = (c & 7) << 4;
      int cl = cb ^ ((row & 7) << 4);
      gload_lds16(kh + (long long)(k0 + row) * 128 + cl, (char*)lK + buf * 16384 + c * 16);
    }
#pragma unroll
    for (int i = 0; i < 4; i++) {
      int c = tid + i * 256;
      int row = c >> 4, cb = (c & 15) << 4;
      int cl = cb ^ ((row & 7) << 4);
      gload_lds16(vh + (long long)row * 2048 + (long long)k0 * 2 + cl, (char*)lV + buf * 16384 + c * 16);
    }
  };

  bf16x8 qa[2];
  {
    const __bf16* qrow = qb + ((long long)bh << 16)
                       + (long long)(q0 + w * 16 + (lane & 15)) * 64 + (lane >> 4) * 8;
    qa[0] = *(const bf16x8*)(qrow);
    qa[1] = *(const bf16x8*)(qrow + 32);
  }
  f32x4 oacc[4] = {};
  float m[4], l[4];
#pragma unroll
  for (int r = 0; r < 4; r++) { m[r] = -3e38f; l[r] = 0.f; }

  const int nt = CAUSAL ? (blockIdx.x / 2 + 1) : 8;
  char* lPw = (char*)lP + w * 4096;

  stageKV(0, 0);
  if (nt > 1) stageKV(1, 1);

  for (int t = 0; t < nt; t++) {
    const int k0 = t * 128;
    if (t < nt - 1) {
      asm volatile("s_waitcnt vmcnt(8)" ::: "memory");
    } else {
      asm volatile("s_waitcnt vmcnt(0)" ::: "memory");
    }
    hard_barrier();
    char* cK = (char*)lK + (t & 1) * 16384;
    char* cV = (char*)lV + (t & 1) * 16384;

    f32x4 sf[8];
#pragma unroll
    for (int f = 0; f < 8; f++) {
      int row = f * 16 + (lane & 15);
      f32x4 s = {};
#pragma unroll
      for (int ks = 0; ks < 2; ks++) {
        int cb = ks * 64 + (lane >> 4) * 16;
        bf16x8 kf = *(const bf16x8*)(cK + row * 128 + (cb ^ ((row & 7) << 4)));
        s = __builtin_amdgcn_mfma_f32_16x16x32_bf16(qa[ks], kf, s, 0, 0, 0);
      }
      sf[f] = s;
    }

    if (!CAUSAL) {
#pragma unroll
      for (int f = 0; f < 8; f++) {
        if (smask[b * 1024 + k0 + f * 16 + (lane & 15)] == 0) {
#pragma unroll
          for (int r = 0; r < 4; r++) sf[f][r] = -1e30f;
        }
      }
    } else if (t == nt - 1) {
#pragma unroll
      for (int f = 0; f < 8; f++) {
        int kc = k0 + f * 16 + (lane & 15);
#pragma unroll
        for (int r = 0; r < 4; r++) {
          int qr = q0 + w * 16 + (lane >> 4) * 4 + r;
          if (kc > qr) sf[f][r] = -1e30f;
        }
      }
    }

    float mt[4];
#pragma unroll
    for (int r = 0; r < 4; r++) {
      float v = sf[0][r];
#pragma unroll
      for (int f = 1; f < 8; f++) v = fmaxf(v, sf[f][r]);
      mt[r] = v;
    }
#pragma unroll
    for (int o = 1; o < 16; o <<= 1)
#pragma unroll
      for (int r = 0; r < 4; r++) mt[r] = fmaxf(mt[r], __shfl_xor(mt[r], o));

    bool need = false;
#pragma unroll
    for (int r = 0; r < 4; r++) need = need || (mt[r] > m[r] + 8.f);
    if (__any(need)) {
      float mn[4], cr[4];
#pragma unroll
      for (int r = 0; r < 4; r++) {
        mn[r] = fmaxf(m[r], mt[r]);
        cr[r] = __expf(m[r] - mn[r]);
        m[r]  = mn[r];
        l[r] *= cr[r];
      }
#pragma unroll
      for (int d = 0; d < 4; d++)
#pragma unroll
        for (int r = 0; r < 4; r++) oacc[d][r] *= cr[r];
    }
    float rs[4] = {0.f, 0.f, 0.f, 0.f};
#pragma unroll
    for (int f = 0; f < 8; f++)
#pragma unroll
      for (int r = 0; r < 4; r++) {
        float p = __expf(sf[f][r] - m[r]);
        sf[f][r] = p;
        rs[r] += p;
      }
#pragma unroll
    for (int o = 1; o < 16; o <<= 1)
#pragma unroll
      for (int r = 0; r < 4; r++) rs[r] += __shfl_xor(rs[r], o);
#pragma unroll
    for (int r = 0; r < 4; r++) l[r] += rs[r];

#pragma unroll
    for (int f = 0; f < 8; f++) {
      int colB = f * 32 + (lane & 15) * 2;
#pragma unroll
      for (int r = 0; r < 4; r++) {
        int row = (lane >> 4) * 4 + r;
        *(__bf16*)(lPw + row * 256 + (colB ^ ((row & 7) << 4))) = (__bf16)sf[f][r];
      }
    }
    asm volatile("s_waitcnt lgkmcnt(0)" ::: "memory");

#pragma unroll
    for (int ks = 0; ks < 4; ks++) {
      int prow = lane & 15;
      int cb = ks * 64 + (lane >> 4) * 16;
      bf16x8 pa = *(const bf16x8*)(lPw + prow * 256 + (cb ^ ((prow & 7) << 4)));
#pragma unroll
      for (int d = 0; d < 4; d++) {
        int vrow = d * 16 + (lane & 15);
        bf16x8 vf = *(const bf16x8*)(cV + vrow * 256 + (cb ^ ((vrow & 7) << 4)));
        oacc[d] = __builtin_amdgcn_mfma_f32_16x16x32_bf16(pa, vf, oacc[d], 0, 0, 0);
      }
    }
    hard_barrier();
    if (t + 2 < nt) stageKV(t & 1, t + 2);
  }

  float inv[4];
#pragma unroll
  for (int r = 0; r < 4; r++) inv[r] = 1.f / l[r];
#pragma unroll
  for (int d = 0; d < 4; d++)
#pragma unroll
    for (int r = 0; r < 4; r++) {
      long long row = b * 1024 + q0 + w * 16 + (lane >> 4) * 4 + r;
      Ob[row * 512 + h * 64 + d * 16 + (lane & 15)] = (__bf16)(oacc[d][r] * inv[r]);
    }
}

// ---------------------------------------------------------------------------
__global__ void transpose_w_kernel(const float* __restrict__ W, __bf16* __restrict__ WT,
                                   int K, int N)
{
  __shared__ float t[32][33];
  long long mz = (long long)blockIdx.z * K * N;
  W += mz; WT += mz;
  int n0 = blockIdx.x * 32, k0 = blockIdx.y * 32;
  int tx = threadIdx.x, ty = threadIdx.y;
#pragma unroll
  for (int i = 0; i < 32; i += 8)
    t[ty + i][tx] = W[(long long)(k0 + ty + i) * N + (n0 + tx)];
  __syncthreads();
#pragma unroll
  for (int i = 0; i < 32; i += 8)
    WT[(long long)(n0 + ty + i) * K + (k0 + tx)] = (__bf16)t[tx][ty + i];
}

__global__ void embed_kernel(const float* __restrict__ emb, const int* __restrict__ idx,
                             __bf16* __restrict__ Xb)
{
  int row = blockIdx.x;
  int s   = row & 1023;
  int tok = idx[row];
  int d0  = threadIdx.x * 4;
  float4 e = *(const float4*)(emb + (long long)tok * 512 + d0);
  const float* ep = (const float*)&e;
  bf16x4 ob;
#pragma unroll
  for (int j = 0; j < 4; j++) {
    int d = d0 + j;
    float div = expf((float)(d & ~1) * (-9.210340371976184f / 512.f));
    float ang = (float)s * div;
    float pe  = (d & 1) ? cosf(ang) : sinf(ang);
    ob[j] = (__bf16)(ep[j] + pe);
  }
  *(bf16x4*)(Xb + (long long)row * 512 + d0) = ob;
}

__global__ void ln_kernel(const __bf16* __restrict__ Xin, const float* __restrict__ Rin,
                          const float* __restrict__ g, const float* __restrict__ b,
                          __bf16* __restrict__ Xbout)
{
  int row = blockIdx.x, lane = threadIdx.x;
  long long base = (long long)row * 512 + lane * 8;
  bf16x8 xv = *(const bf16x8*)(Xin + base);
  float x[8];
#pragma unroll
  for (int i = 0; i < 8; i++) x[i] = (float)xv[i];
  if (Rin) {
    float4 r0 = *(const float4*)(Rin + base);
    float4 r1 = *(const float4*)(Rin + base + 4);
    x[0] += r0.x; x[1] += r0.y; x[2] += r0.z; x[3] += r0.w;
    x[4] += r1.x; x[5] += r1.y; x[6] += r1.z; x[7] += r1.w;
  }
  float s = 0.f;
#pragma unroll
  for (int i = 0; i < 8; i++) s += x[i];
#pragma unroll
  for (int o = 32; o > 0; o >>= 1) s += __shfl_xor(s, o);
  float mean = s * (1.f / 512.f);
  float v = 0.f;
#pragma unroll
  for (int i = 0; i < 8; i++) { x[i] -= mean; v += x[i] * x[i]; }
#pragma unroll
  for (int o = 32; o > 0; o >>= 1) v += __shfl_xor(v, o);
  float inv = rsqrtf(v * (1.f / 512.f) + 1e-5f);
  int d0 = lane * 8;
  float gg[8], bb[8];
  *(float4*)gg       = *(const float4*)(g + d0);
  *(float4*)(gg + 4) = *(const float4*)(g + d0 + 4);
  *(float4*)bb       = *(const float4*)(b + d0);
  *(float4*)(bb + 4) = *(const float4*)(b + d0 + 4);
  bf16x8 yb;
#pragma unroll
  for (int i = 0; i < 8; i++)
    yb[i] = (__bf16)(x[i] * inv * gg[i] + bb[i]);
  *(bf16x8*)(Xbout + base) = yb;
}

// ---------------------------------------------------------------------------
extern "C" void kernel_launch(void* const* d_in, const int* in_sizes, int n_in,
                              void* d_out, int out_size, void* d_ws, size_t ws_size,
                              hipStream_t stream)
{
  (void)in_sizes; (void)n_in; (void)out_size; (void)ws_size;
  const float* src_emb    = (const float*)d_in[0];
  const float* tgt_emb    = (const float*)d_in[1];
  const float* enc_attn_w = (const float*)d_in[2];
  const float* enc_attn_b = (const float*)d_in[3];
  const float* enc_ffn_w1 = (const float*)d_in[4];
  const float* enc_ffn_b1 = (const float*)d_in[5];
  const float* enc_ffn_w2 = (const float*)d_in[6];
  const float* enc_ffn_b2 = (const float*)d_in[7];
  const float* enc_ln_g   = (const float*)d_in[8];
  const float* enc_ln_b   = (const float*)d_in[9];
  const float* enc_fg     = (const float*)d_in[10];
  const float* enc_fb     = (const float*)d_in[11];
  const float* dec_self_w = (const float*)d_in[12];
  const float* dec_self_b = (const float*)d_in[13];
  const float* dec_src_w  = (const float*)d_in[14];
  const float* dec_src_b  = (const float*)d_in[15];
  const float* dec_ffn_w1 = (const float*)d_in[16];
  const float* dec_ffn_b1 = (const float*)d_in[17];
  const float* dec_ffn_w2 = (const float*)d_in[18];
  const float* dec_ffn_b2 = (const float*)d_in[19];
  const float* dec_ln_g   = (const float*)d_in[20];
  const float* dec_ln_b   = (const float*)d_in[21];
  const float* dec_fg     = (const float*)d_in[22];
  const float* dec_fb     = (const float*)d_in[23];
  const float* gen_w      = (const float*)d_in[24];
  const float* gen_b      = (const float*)d_in[25];
  const int*   src        = (const int*)d_in[26];
  const int*   tgt        = (const int*)d_in[27];
  const int*   src_mask   = (const int*)d_in[28];

  float* out = (float*)d_out;

  // ---- workspace ----
  char* wp = (char*)d_ws;
  auto alloc = [&](size_t bytes) { void* p = (void*)wp; wp += (bytes + 255) & ~(size_t)255; return p; };
  __bf16* TWea = (__bf16*)alloc(24ull * 262144 * 2);    // enc attn [6][4][512][512]^T
  __bf16* TWe1 = (__bf16*)alloc(6ull * 1048576 * 2);
  __bf16* TWe2 = (__bf16*)alloc(6ull * 1048576 * 2);
  __bf16* TWds = (__bf16*)alloc(24ull * 262144 * 2);
  __bf16* TWdx = (__bf16*)alloc(24ull * 262144 * 2);
  __bf16* TWd1 = (__bf16*)alloc(6ull * 1048576 * 2);
  __bf16* TWd2 = (__bf16*)alloc(6ull * 1048576 * 2);
  __bf16* Xb   = (__bf16*)alloc(4096ull * 512 * 2);     // bf16 residual stream
  __bf16* MEMb = (__bf16*)alloc(4096ull * 512 * 2);
  float*  R    = (float*) alloc(4096ull * 512 * 4);     // sublayer branch fp32
  __bf16* qb   = (__bf16*)alloc(32ull * 1024 * 64 * 2); // } union with Fb
  __bf16* kb   = (__bf16*)alloc(32ull * 1024 * 64 * 2);
  __bf16* vt   = (__bf16*)alloc(32ull * 1024 * 64 * 2);
  __bf16* Ob   = (__bf16*)alloc(4096ull * 512 * 2);
  __bf16* Fb   = qb;                                    // ffn hidden bf16 [4096][2048]
  __bf16* GENT = TWea;                                  // gen_w^T, after encoder

  // ---- bulk weight transposes ----
  transpose_w_kernel<<<dim3(16, 16, 24), dim3(32, 8), 0, stream>>>(enc_attn_w, TWea, 512, 512);
  transpose_w_kernel<<<dim3(64, 16, 6),  dim3(32, 8), 0, stream>>>(enc_ffn_w1, TWe1, 512, 2048);
  transpose_w_kernel<<<dim3(16, 64, 6),  dim3(32, 8), 0, stream>>>(enc_ffn_w2, TWe2, 2048, 512);
  transpose_w_kernel<<<dim3(16, 16, 24), dim3(32, 8), 0, stream>>>(dec_self_w, TWds, 512, 512);
  transpose_w_kernel<<<dim3(16, 16, 24), dim3(32, 8), 0, stream>>>(dec_src_w,  TWdx, 512, 512);
  transpose_w_kernel<<<dim3(64, 16, 6),  dim3(32, 8), 0, stream>>>(dec_ffn_w1, TWd1, 512, 2048);
  transpose_w_kernel<<<dim3(16, 64, 6),  dim3(32, 8), 0, stream>>>(dec_ffn_w2, TWd2, 2048, 512);

  // attention sublayer: single unified QKV dispatch; writes R.
  auto attention = [&](const __bf16* wt, const float* bptr, int causal,
                       const __bf16* Aq, const __bf16* Akv) {
    gemm2_kernel<2><<<dim3(32, 12), 256, 0, stream>>>(
        Aq, Akv, 512, wt, 512, nullptr, 0, bptr, 512, qb, kb, vt);
    if (causal)
      flash_kernel<1><<<dim3(16, 32), 256, 0, stream>>>(qb, kb, vt, nullptr, Ob);
    else
      flash_kernel<0><<<dim3(16, 32), 256, 0, stream>>>(qb, kb, vt, src_mask, Ob);
    gemm_kernel<<<dim3(32, 8), 256, 0, stream>>>(
        Ob, 512, wt + 3 * 262144, 512, R, 512, bptr + 3 * 512, 512);
  };

  auto ffn = [&](const __bf16* w1t, const float* b1, const __bf16* w2t, const float* b2) {
    gemm2_kernel<1><<<dim3(32, 16), 256, 0, stream>>>(
        Xb, Xb, 512, w1t, 512, Fb, 2048, b1, 512, nullptr, nullptr, nullptr);
    gemm_kernel<<<dim3(32, 8), 256, 0, stream>>>(
        Fb, 2048, w2t, 2048, R, 512, b2, 2048);
  };

  // ---------------- encoder ----------------
  embed_kernel<<<4096, 128, 0, stream>>>(src_emb, src, Xb);
  for (int i = 0; i < 6; i++) {
    attention(TWea + (long long)i * 1048576, enc_attn_b + i * 2048, 0, Xb, Xb);
    ln_kernel<<<4096, 64, 0, stream>>>(Xb, R, enc_ln_g + i * 1024, enc_ln_b + i * 1024, Xb);
    ffn(TWe1 + (long long)i * 1048576, enc_ffn_b1 + i * 2048,
        TWe2 + (long long)i * 1048576, enc_ffn_b2 + i * 512);
    ln_kernel<<<4096, 64, 0, stream>>>(Xb, R, enc_ln_g + i * 1024 + 512, enc_ln_b + i * 1024 + 512, Xb);
  }
  ln_kernel<<<4096, 64, 0, stream>>>(Xb, nullptr, enc_fg, enc_fb, MEMb);

  transpose_w_kernel<<<dim3(1000, 16, 1), dim3(32, 8), 0, stream>>>(gen_w, GENT, 512, 32000);

  // ---------------- decoder ----------------
  embed_kernel<<<4096, 128, 0, stream>>>(tgt_emb, tgt, Xb);
  for (int i = 0; i < 6; i++) {
    attention(TWds + (long long)i * 1048576, dec_self_b + i * 2048, 1, Xb, Xb);
    ln_kernel<<<4096, 64, 0, stream>>>(Xb, R, dec_ln_g + i * 1536, dec_ln_b + i * 1536, Xb);

    attention(TWdx + (long long)i * 1048576, dec_src_b + i * 2048, 0, Xb, MEMb);
    ln_kernel<<<4096, 64, 0, stream>>>(Xb, R, dec_ln_g + i * 1536 + 512, dec_ln_b + i * 1536 + 512, Xb);

    ffn(TWd1 + (long long)i * 1048576, dec_ffn_b1 + i * 2048,
        TWd2 + (long long)i * 1048576, dec_ffn_b2 + i * 512);
    ln_kernel<<<4096, 64, 0, stream>>>(Xb, R, dec_ln_g + i * 1536 + 1024, dec_ln_b + i * 1536 + 1024, Xb);
  }
  ln_kernel<<<4096, 64, 0, stream>>>(Xb, nullptr, dec_fg, dec_fb, Xb);

  // ---------------- generator: 256^2 8-wave 4-phase ----------------
  gemm256_kernel<<<dim3(16, 125), 512, 0, stream>>>(
      Xb, 512, GENT, 512, out, 32000, gen_b, 512);
}

// Round 11
// 1783.441 us; speedup vs baseline: 1.1833x; 1.0297x over previous
//
#include <hip/hip_runtime.h>

// ---------------------------------------------------------------------------
// Transformer (enc-dec, D=512, H=8, N=6, DFF=2048, B=4, S=T=1024, V=32000)
// GEMMs: 128x128 PIPE2 (counted vmcnt(8), T2 swizzle) for N>=1024;
//        128x64 PIPE3 (counted vmcnt(6)) for N=512 with FUSED residual-add
//        epilogue (writes bf16 Xs = acc + bias + Xb).
// Generator: 256x256 8-wave 4-quadrant-phase kernel.
// Flash: counted-vmcnt PIPE2 KV staging + defer-max + causal load-balance.
// bf16 residual stream; slim LN.
// ---------------------------------------------------------------------------

typedef __bf16 bf16x8 __attribute__((ext_vector_type(8)));
typedef __bf16 bf16x4 __attribute__((ext_vector_type(4)));
typedef float  f32x4  __attribute__((ext_vector_type(4)));

__device__ __forceinline__ void gload_lds16(const void* g, void* l) {
  __builtin_amdgcn_global_load_lds((__attribute__((address_space(1))) void*)g,
                                   (__attribute__((address_space(3))) void*)l,
                                   16, 0, 0);
}

__device__ __forceinline__ void hard_barrier() {
  asm volatile("" ::: "memory");
  __builtin_amdgcn_sched_barrier(0);
  __builtin_amdgcn_s_barrier();
  __builtin_amdgcn_sched_barrier(0);
  asm volatile("" ::: "memory");
}

// ---------------------------------------------------------------------------
// Generator GEMM: 256x256 tile, 512 thr / 8 waves (2M x 4N), BK=64.
__global__ __launch_bounds__(512, 2)
void gemm256_kernel(const __bf16* __restrict__ A, int lda,
                    const __bf16* __restrict__ BT, int ldb,
                    float* __restrict__ C, int ldc,
                    const float* __restrict__ bias, int K)
{
  __shared__ char ldsraw[131072];              // 2 slots x 64 KB
  const int tid  = threadIdx.x;
  const int lane = tid & 63, wid = tid >> 6;
  const int wr = wid >> 2, wc = wid & 3;       // 2 x 4 wave grid
  const int bm = blockIdx.x * 256, bn = blockIdx.y * 256;

  auto stage = [&](int slot, int kt) {
    const char* Ag = (const char*)A;
    const char* Bg = (const char*)BT;
    char* base = ldsraw + slot * 65536;
    const long long k0b = (long long)kt * 128;
#pragma unroll
    for (int i = 0; i < 4; i++) {
      int t = tid + i * 512;
      int row = t >> 3, cb = (t & 7) << 4;
      int src = cb ^ ((row & 7) << 4);
      gload_lds16(Ag + ((long long)(bm + row) * lda) * 2 + k0b + src, base + t * 16);
    }
#pragma unroll
    for (int i = 0; i < 4; i++) {
      int t = tid + i * 512;
      int row = t >> 3, cb = (t & 7) << 4;
      int src = cb ^ ((row & 7) << 4);
      gload_lds16(Bg + ((long long)(bn + row) * ldb) * 2 + k0b + src,
                  base + 32768 + t * 16);
    }
  };

  f32x4 acc[8][4] = {};
  const int NT = K / 64;

  stage(0, 0);
  stage(1, 1);

  for (int kt = 0; kt < NT; kt++) {
    if (kt < NT - 1) {
      asm volatile("s_waitcnt vmcnt(8)" ::: "memory");
    } else {
      asm volatile("s_waitcnt vmcnt(0)" ::: "memory");
    }
    hard_barrier();
    const char* sA = ldsraw + (kt & 1) * 65536;
    const char* sB = sA + 32768;
#pragma unroll
    for (int q = 0; q < 4; q++) {
      const int qr = q >> 1, qc = q & 1;
      bf16x8 af[4][2], bf[2][2];
#pragma unroll
      for (int i = 0; i < 4; i++) {
        int row = wr * 128 + (qr * 4 + i) * 16 + (lane & 15);
#pragma unroll
        for (int kk = 0; kk < 2; kk++) {
          int g = kk * 64 + (lane >> 4) * 16;
          af[i][kk] = *(const bf16x8*)(sA + row * 128 + (g ^ ((row & 7) << 4)));
        }
      }
#pragma unroll
      for (int j = 0; j < 2; j++) {
        int row = wc * 64 + (qc * 2 + j) * 16 + (lane & 15);
#pragma unroll
        for (int kk = 0; kk < 2; kk++) {
          int g = kk * 64 + (lane >> 4) * 16;
          bf[j][kk] = *(const bf16x8*)(sB + row * 128 + (g ^ ((row & 7) << 4)));
        }
      }
      __builtin_amdgcn_s_barrier();
      asm volatile("s_waitcnt lgkmcnt(0)" ::: "memory");
      __builtin_amdgcn_sched_barrier(0);
      __builtin_amdgcn_s_setprio(1);
#pragma unroll
      for (int kk = 0; kk < 2; kk++)
#pragma unroll
        for (int i = 0; i < 4; i++)
#pragma unroll
          for (int j = 0; j < 2; j++)
            acc[qr * 4 + i][qc * 2 + j] = __builtin_amdgcn_mfma_f32_16x16x32_bf16(
                af[i][kk], bf[j][kk], acc[qr * 4 + i][qc * 2 + j], 0, 0, 0);
      __builtin_amdgcn_s_setprio(0);
    }
    hard_barrier();
    if (kt + 2 < NT) stage(kt & 1, kt + 2);
  }

  // ---- epilogue: 4 chunks of 64 rows; LDS transpose stride 260 fl ----
  float* ct = (float*)ldsraw;
#pragma unroll
  for (int c = 0; c < 4; c++) {
    __syncthreads();
    if (wr == (c >> 1)) {
      const int ib = (c & 1) * 4;
#pragma unroll
      for (int i = 0; i < 4; i++) {
#pragma unroll
        for (int j = 0; j < 4; j++) {
          int lrow = i * 16 + (lane >> 4) * 4;
          int lcol = wc * 64 + j * 16 + (lane & 15);
          float bv = bias[bn + lcol];
#pragma unroll
          for (int r = 0; r < 4; r++)
            ct[(lrow + r) * 260 + lcol] = acc[ib + i][j][r] + bv;
        }
      }
    }
    __syncthreads();
#pragma unroll
    for (int it = 0; it < 8; it++) {
      int idx = tid + it * 512;
      int row = idx >> 6, c4 = (idx & 63) * 4;
      f32x4 v = *(const f32x4*)(ct + row * 260 + c4);
      *(f32x4*)(C + (long long)(bm + c * 64 + row) * ldc + bn + c4) = v;
    }
  }
}

// ---------------------------------------------------------------------------
// PIPE2 128x128 GEMM. EPI 1: bf16+ReLU (FFN1). EPI 2: qkv routing with
// per-column-tile A select (cols<512 -> A, else Akv).
template<int EPI>
__global__ __launch_bounds__(256)
void gemm2_kernel(const __bf16* __restrict__ A, const __bf16* __restrict__ Akv,
                  int lda,
                  const __bf16* __restrict__ BT, int ldb,
                  void* __restrict__ Cv, int ldc,
                  const float* __restrict__ bias, int K,
                  __bf16* __restrict__ qb, __bf16* __restrict__ kb,
                  __bf16* __restrict__ vt)
{
  constexpr int BM = 128, BN = 128, BK = 64;
  constexpr int WM = 64, WN = 64, FM = 4, FN = 4;
  constexpr int SLOT = 2 * BM * BK;
  __shared__ char ldsraw[65536];
  __bf16* lds = (__bf16*)ldsraw;
  const int tid  = threadIdx.x;
  const int lane = tid & 63, wave = tid >> 6;
  const int wr = wave >> 1, wc = wave & 1;
  const int bm = blockIdx.x * BM, bn = blockIdx.y * BN;
  const __bf16* Ause = (EPI == 2 && blockIdx.y >= 4) ? Akv : A;

  auto stage = [&](int slot, int kt) {
    const char* Ag = (const char*)Ause;
    const char* Bg = (const char*)BT;
    char* base = (char*)(lds + slot * SLOT);
    const long long k0b = (long long)kt * (BK * 2);
#pragma unroll
    for (int i = 0; i < 4; i++) {
      int t = tid + i * 256;
      int row = t >> 3, cb = (t & 7) << 4;
      int src = cb ^ ((row & 7) << 4);
      gload_lds16(Ag + ((long long)(bm + row) * lda) * 2 + k0b + src, base + t * 16);
    }
#pragma unroll
    for (int i = 0; i < 4; i++) {
      int t = tid + i * 256;
      int row = t >> 3, cb = (t & 7) << 4;
      int src = cb ^ ((row & 7) << 4);
      gload_lds16(Bg + ((long long)(bn + row) * ldb) * 2 + k0b + src,
                  base + BM * BK * 2 + t * 16);
    }
  };

  f32x4 acc[FM][FN] = {};
  const int NT = K / BK;

  stage(0, 0);
  stage(1, 1);

  for (int t = 0; t < NT; t++) {
    if (t < NT - 1) {
      asm volatile("s_waitcnt vmcnt(8)" ::: "memory");
    } else {
      asm volatile("s_waitcnt vmcnt(0)" ::: "memory");
    }
    hard_barrier();
    const char* sA = (const char*)(lds + (t & 1) * SLOT);
    const char* sB = sA + BM * BK * 2;
#pragma unroll
    for (int kk = 0; kk < 2; kk++) {
      const int g = kk * 64 + (lane >> 4) * 16;
      bf16x8 af[FM], bfr[FN];
#pragma unroll
      for (int i = 0; i < FM; i++) {
        int row = wr * WM + i * 16 + (lane & 15);
        af[i] = *(const bf16x8*)(sA + row * 128 + (g ^ ((row & 7) << 4)));
      }
#pragma unroll
      for (int j = 0; j < FN; j++) {
        int row = wc * WN + j * 16 + (lane & 15);
        bfr[j] = *(const bf16x8*)(sB + row * 128 + (g ^ ((row & 7) << 4)));
      }
      __builtin_amdgcn_s_setprio(1);
#pragma unroll
      for (int i = 0; i < FM; i++)
#pragma unroll
        for (int j = 0; j < FN; j++)
          acc[i][j] = __builtin_amdgcn_mfma_f32_16x16x32_bf16(af[i], bfr[j], acc[i][j], 0, 0, 0);
      __builtin_amdgcn_s_setprio(0);
    }
    hard_barrier();
    if (t + 2 < NT) stage(t & 1, t + 2);
  }

#pragma unroll
  for (int i = 0; i < FM; i++) {
#pragma unroll
    for (int j = 0; j < FN; j++) {
      int row0 = bm + wr * WM + i * 16 + (lane >> 4) * 4;
      int col  = bn + wc * WN + j * 16 + (lane & 15);
      float bv = bias ? bias[col] : 0.f;
      if constexpr (EPI == 2) {
        int z = col >> 9;
        int cw = col & 511;
        int b = row0 >> 10, s = row0 & 1023;
        int h = cw >> 6, dk = cw & 63;
        long long bh = b * 8 + h;
        if (z == 2) {
          bf16x4 vv;
#pragma unroll
          for (int r = 0; r < 4; r++) vv[r] = (__bf16)(acc[i][j][r] + bv);
          *(bf16x4*)(vt + (bh << 16) + (dk << 10) + s) = vv;
        } else {
          __bf16* dst = (z == 0) ? qb : kb;
          float sc = (z == 0) ? 0.125f : 1.0f;
#pragma unroll
          for (int r = 0; r < 4; r++)
            dst[(bh << 16) + ((long long)(s + r) << 6) + dk] = (__bf16)((acc[i][j][r] + bv) * sc);
        }
      } else {
        __bf16* C = (__bf16*)Cv;
#pragma unroll
        for (int r = 0; r < 4; r++)
          C[(long long)(row0 + r) * ldc + col] = (__bf16)fmaxf(acc[i][j][r] + bv, 0.f);
      }
    }
  }
}

// ---------------------------------------------------------------------------
// PIPE3 128x64 GEMM with FUSED residual epilogue: Xs = bf16(acc + bias + Xbase).
// Used by O-proj (K=512) and FFN2 (K=2048). ldc = 512.
__global__ __launch_bounds__(256)
void gemm_kernel(const __bf16* __restrict__ A, int lda,
                 const __bf16* __restrict__ BT, int ldb,
                 const __bf16* __restrict__ Xbase,
                 __bf16* __restrict__ Xs, int ldc,
                 const float* __restrict__ bias, int K)
{
  constexpr int BM = 128, BN = 64, BK = 64;
  constexpr int WM = 64, WN = 32, FM = 4, FN = 2;
  constexpr int LA = (BM * BK) / 2048;
  constexpr int LB = (BN * BK) / 2048;
  constexpr int SLOT = (BM + BN) * BK;
  __shared__ __bf16 lds[3 * SLOT];
  const int tid  = threadIdx.x;
  const int lane = tid & 63, wave = tid >> 6;
  const int wr = wave >> 1, wc = wave & 1;
  const int bm = blockIdx.x * BM, bn = blockIdx.y * BN;

  auto stage = [&](int slot, int kt) {
    const char* Ag = (const char*)A;
    const char* Bg = (const char*)BT;
    char* base = (char*)(lds + slot * SLOT);
    const long long k0b = (long long)kt * (BK * 2);
#pragma unroll
    for (int i = 0; i < LA; i++) {
      int t = tid + i * 256;
      int row = t >> 3, cb = (t & 7) << 4;
      int src = cb ^ ((row & 7) << 4);
      gload_lds16(Ag + ((long long)(bm + row) * lda) * 2 + k0b + src, base + t * 16);
    }
#pragma unroll
    for (int i = 0; i < LB; i++) {
      int t = tid + i * 256;
      int row = t >> 3, cb = (t & 7) << 4;
      int src = cb ^ ((row & 7) << 4);
      gload_lds16(Bg + ((long long)(bn + row) * ldb) * 2 + k0b + src,
                  base + BM * BK * 2 + t * 16);
    }
  };

  f32x4 acc[FM][FN] = {};
  const int NT = K / BK;

  stage(0, 0);
  stage(1, 1);

  for (int t = 0; t < NT; t++) {
    if (t < NT - 1) {
      asm volatile("s_waitcnt vmcnt(6)" ::: "memory");
    } else {
      asm volatile("s_waitcnt vmcnt(0)" ::: "memory");
    }
    hard_barrier();
    if (t + 2 < NT) stage((t + 2) % 3, t + 2);
    const char* sA = (const char*)(lds + (t % 3) * SLOT);
    const char* sB = sA + BM * BK * 2;
#pragma unroll
    for (int kk = 0; kk < 2; kk++) {
      const int g = kk * 64 + (lane >> 4) * 16;
      bf16x8 af[FM], bfr[FN];
#pragma unroll
      for (int i = 0; i < FM; i++) {
        int row = wr * WM + i * 16 + (lane & 15);
        af[i] = *(const bf16x8*)(sA + row * 128 + (g ^ ((row & 7) << 4)));
      }
#pragma unroll
      for (int j = 0; j < FN; j++) {
        int row = wc * WN + j * 16 + (lane & 15);
        bfr[j] = *(const bf16x8*)(sB + row * 128 + (g ^ ((row & 7) << 4)));
      }
      __builtin_amdgcn_s_setprio(1);
#pragma unroll
      for (int i = 0; i < FM; i++)
#pragma unroll
        for (int j = 0; j < FN; j++)
          acc[i][j] = __builtin_amdgcn_mfma_f32_16x16x32_bf16(af[i], bfr[j], acc[i][j], 0, 0, 0);
      __builtin_amdgcn_s_setprio(0);
    }
  }

#pragma unroll
  for (int i = 0; i < FM; i++) {
#pragma unroll
    for (int j = 0; j < FN; j++) {
      int row0 = bm + wr * WM + i * 16 + (lane >> 4) * 4;
      int col  = bn + wc * WN + j * 16 + (lane & 15);
      float bv = bias[col];
#pragma unroll
      for (int r = 0; r < 4; r++) {
        long long off = (long long)(row0 + r) * ldc + col;
        Xs[off] = (__bf16)(acc[i][j][r] + bv + (float)Xbase[off]);
      }
    }
  }
}

// ---------------------------------------------------------------------------
// Flash attention: counted-vmcnt PIPE2 KV staging + defer-max (THR=8).
// Causal: q-tile remapped (by<16 ? bx : 15-bx) so same-CU block pairs sum to
// a constant 17 KV-tiles (load balance).
template<int CAUSAL>
__global__ __launch_bounds__(256)
void flash_kernel(const __bf16* __restrict__ qb, const __bf16* __restrict__ kb,
                  const __bf16* __restrict__ vt, const int* __restrict__ smask,
                  __bf16* __restrict__ Ob)
{
  __shared__ __bf16 lK[2 * 128 * 64];
  __shared__ __bf16 lV[2 * 64 * 128];
  __shared__ __bf16 lP[4][16 * 128];
  const int bh = blockIdx.y;
  const int b = bh >> 3, h = bh & 7;
  const int qt = CAUSAL ? ((blockIdx.y < 16) ? blockIdx.x : 15 - blockIdx.x)
                        : blockIdx.x;
  const int q0 = qt * 64;
  const int tid = threadIdx.x, lane = tid & 63, w = tid >> 6;
  const char* kh = (const char*)(kb + ((long long)bh << 16));
  const char* vh = (const char*)(vt + ((long long)bh << 16));

  auto stageKV = [&](int buf, int t) {
    int k0 = t * 128;
#pragma unroll
    for (int i = 0; i < 4; i++) {
      int c = tid + i * 256;
      int row = c >> 3, cb = (c & 7) << 4;
      int cl = cb ^ ((row & 7) << 4);
      gload_lds16(kh + (long long)(k0 + row) * 128 + cl, (char*)lK + buf * 16384 + c * 16);
    }
#pragma unroll
    for (int i = 0; i < 4; i++) {
      int c = tid + i * 256;
      int row = c >> 4, cb = (c & 15) << 4;
      int cl = cb ^ ((row & 7) << 4);
      gload_lds16(vh + (long long)row * 2048 + (long long)k0 * 2 + cl, (char*)lV + buf * 16384 + c * 16);
    }
  };

  bf16x8 qa[2];
  {
    const __bf16* qrow = qb + ((long long)bh << 16)
                       + (long long)(q0 + w * 16 + (lane & 15)) * 64 + (lane >> 4) * 8;
    qa[0] = *(const bf16x8*)(qrow);
    qa[1] = *(const bf16x8*)(qrow + 32);
  }
  f32x4 oacc[4] = {};
  float m[4], l[4];
#pragma unroll
  for (int r = 0; r < 4; r++) { m[r] = -3e38f; l[r] = 0.f; }

  const int nt = CAUSAL ? (qt / 2 + 1) : 8;
  char* lPw = (char*)lP + w * 4096;

  stageKV(0, 0);
  if (nt > 1) stageKV(1, 1);

  for (int t = 0; t < nt; t++) {
    const int k0 = t * 128;
    if (t < nt - 1) {
      asm volatile("s_waitcnt vmcnt(8)" ::: "memory");
    } else {
      asm volatile("s_waitcnt vmcnt(0)" ::: "memory");
    }
    hard_barrier();
    char* cK = (char*)lK + (t & 1) * 16384;
    char* cV = (char*)lV + (t & 1) * 16384;

    f32x4 sf[8];
#pragma unroll
    for (int f = 0; f < 8; f++) {
      int row = f * 16 + (lane & 15);
      f32x4 s = {};
#pragma unroll
      for (int ks = 0; ks < 2; ks++) {
        int cb = ks * 64 + (lane >> 4) * 16;
        bf16x8 kf = *(const bf16x8*)(cK + row * 128 + (cb ^ ((row & 7) << 4)));
        s = __builtin_amdgcn_mfma_f32_16x16x32_bf16(qa[ks], kf, s, 0, 0, 0);
      }
      sf[f] = s;
    }

    if (!CAUSAL) {
#pragma unroll
      for (int f = 0; f < 8; f++) {
        if (smask[b * 1024 + k0 + f * 16 + (lane & 15)] == 0) {
#pragma unroll
          for (int r = 0; r < 4; r++) sf[f][r] = -1e30f;
        }
      }
    } else if (t == nt - 1) {
#pragma unroll
      for (int f = 0; f < 8; f++) {
        int kc = k0 + f * 16 + (lane & 15);
#pragma unroll
        for (int r = 0; r < 4; r++) {
          int qr = q0 + w * 16 + (lane >> 4) * 4 + r;
          if (kc > qr) sf[f][r] = -1e30f;
        }
      }
    }

    float mt[4];
#pragma unroll
    for (int r = 0; r < 4; r++) {
      float v = sf[0][r];
#pragma unroll
      for (int f = 1; f < 8; f++) v = fmaxf(v, sf[f][r]);
      mt[r] = v;
    }
#pragma unroll
    for (int o = 1; o < 16; o <<= 1)
#pragma unroll
      for (int r = 0; r < 4; r++) mt[r] = fmaxf(mt[r], __shfl_xor(mt[r], o));

    bool need = false;
#pragma unroll
    for (int r = 0; r < 4; r++) need = need || (mt[r] > m[r] + 8.f);
    if (__any(need)) {
      float mn[4], cr[4];
#pragma unroll
      for (int r = 0; r < 4; r++) {
        mn[r] = fmaxf(m[r], mt[r]);
        cr[r] = __expf(m[r] - mn[r]);
        m[r]  = mn[r];
        l[r] *= cr[r];
      }
#pragma unroll
      for (int d = 0; d < 4; d++)
#pragma unroll
        for (int r = 0; r < 4; r++) oacc[d][r] *= cr[r];
    }
    float rs[4] = {0.f, 0.f, 0.f, 0.f};
#pragma unroll
    for (int f = 0; f < 8; f++)
#pragma unroll
      for (int r = 0; r < 4; r++) {
        float p = __expf(sf[f][r] - m[r]);
        sf[f][r] = p;
        rs[r] += p;
      }
#pragma unroll
    for (int o = 1; o < 16; o <<= 1)
#pragma unroll
      for (int r = 0; r < 4; r++) rs[r] += __shfl_xor(rs[r], o);
#pragma unroll
    for (int r = 0; r < 4; r++) l[r] += rs[r];

#pragma unroll
    for (int f = 0; f < 8; f++) {
      int colB = f * 32 + (lane & 15) * 2;
#pragma unroll
      for (int r = 0; r < 4; r++) {
        int row = (lane >> 4) * 4 + r;
        *(__bf16*)(lPw + row * 256 + (colB ^ ((row & 7) << 4))) = (__bf16)sf[f][r];
      }
    }
    asm volatile("s_waitcnt lgkmcnt(0)" ::: "memory");

#pragma unroll
    for (int ks = 0; ks < 4; ks++) {
      int prow = lane & 15;
      int cb = ks * 64 + (lane >> 4) * 16;
      bf16x8 pa = *(const bf16x8*)(lPw + prow * 256 + (cb ^ ((prow & 7) << 4)));
#pragma unroll
      for (int d = 0; d < 4; d++) {
        int vrow = d * 16 + (lane & 15);
        bf16x8 vf = *(const bf16x8*)(cV + vrow * 256 + (cb ^ ((vrow & 7) << 4)));
        oacc[d] = __builtin_amdgcn_mfma_f32_16x16x32_bf16(pa, vf, oacc[d], 0, 0, 0);
      }
    }
    hard_barrier();
    if (t + 2 < nt) stageKV(t & 1, t + 2);
  }

  float inv[4];
#pragma unroll
  for (int r = 0; r < 4; r++) inv[r] = 1.f / l[r];
#pragma unroll
  for (int d = 0; d < 4; d++)
#pragma unroll
    for (int r = 0; r < 4; r++) {
      long long row = b * 1024 + q0 + w * 16 + (lane >> 4) * 4 + r;
      Ob[row * 512 + h * 64 + d * 16 + (lane & 15)] = (__bf16)(oacc[d][r] * inv[r]);
    }
}

// ---------------------------------------------------------------------------
__global__ void transpose_w_kernel(const float* __restrict__ W, __bf16* __restrict__ WT,
                                   int K, int N)
{
  __shared__ float t[32][33];
  long long mz = (long long)blockIdx.z * K * N;
  W += mz; WT += mz;
  int n0 = blockIdx.x * 32, k0 = blockIdx.y * 32;
  int tx = threadIdx.x, ty = threadIdx.y;
#pragma unroll
  for (int i = 0; i < 32; i += 8)
    t[ty + i][tx] = W[(long long)(k0 + ty + i) * N + (n0 + tx)];
  __syncthreads();
#pragma unroll
  for (int i = 0; i < 32; i += 8)
    WT[(long long)(n0 + ty + i) * K + (k0 + tx)] = (__bf16)t[tx][ty + i];
}

__global__ void embed_kernel(const float* __restrict__ emb, const int* __restrict__ idx,
                             __bf16* __restrict__ Xb)
{
  int row = blockIdx.x;
  int s   = row & 1023;
  int tok = idx[row];
  int d0  = threadIdx.x * 4;
  float4 e = *(const float4*)(emb + (long long)tok * 512 + d0);
  const float* ep = (const float*)&e;
  bf16x4 ob;
#pragma unroll
  for (int j = 0; j < 4; j++) {
    int d = d0 + j;
    float div = expf((float)(d & ~1) * (-9.210340371976184f / 512.f));
    float ang = (float)s * div;
    float pe  = (d & 1) ? cosf(ang) : sinf(ang);
    ob[j] = (__bf16)(ep[j] + pe);
  }
  *(bf16x4*)(Xb + (long long)row * 512 + d0) = ob;
}

// LayerNorm(bf16 in) * g + b -> bf16. 4 rows/block, 256 thr. Grid 1024.
__global__ __launch_bounds__(256)
void ln_kernel(const __bf16* __restrict__ Xin,
               const float* __restrict__ g, const float* __restrict__ b,
               __bf16* __restrict__ Xbout)
{
  int row = blockIdx.x * 4 + (threadIdx.x >> 6);
  int lane = threadIdx.x & 63;
  long long base = (long long)row * 512 + lane * 8;
  bf16x8 xv = *(const bf16x8*)(Xin + base);
  float x[8];
#pragma unroll
  for (int i = 0; i < 8; i++) x[i] = (float)xv[i];
  float s = 0.f;
#pragma unroll
  for (int i = 0; i < 8; i++) s += x[i];
#pragma unroll
  for (int o = 32; o > 0; o >>= 1) s += __shfl_xor(s, o);
  float mean = s * (1.f / 512.f);
  float v = 0.f;
#pragma unroll
  for (int i = 0; i < 8; i++) { x[i] -= mean; v += x[i] * x[i]; }
#pragma unroll
  for (int o = 32; o > 0; o >>= 1) v += __shfl_xor(v, o);
  float inv = rsqrtf(v * (1.f / 512.f) + 1e-5f);
  int d0 = lane * 8;
  float gg[8], bb[8];
  *(float4*)gg       = *(const float4*)(g + d0);
  *(float4*)(gg + 4) = *(const float4*)(g + d0 + 4);
  *(float4*)bb       = *(const float4*)(b + d0);
  *(float4*)(bb + 4) = *(const float4*)(b + d0 + 4);
  bf16x8 yb;
#pragma unroll
  for (int i = 0; i < 8; i++)
    yb[i] = (__bf16)(x[i] * inv * gg[i] + bb[i]);
  *(bf16x8*)(Xbout + base) = yb;
}

// ---------------------------------------------------------------------------
extern "C" void kernel_launch(void* const* d_in, const int* in_sizes, int n_in,
                              void* d_out, int out_size, void* d_ws, size_t ws_size,
                              hipStream_t stream)
{
  (void)in_sizes; (void)n_in; (void)out_size; (void)ws_size;
  const float* src_emb    = (const float*)d_in[0];
  const float* tgt_emb    = (const float*)d_in[1];
  const float* enc_attn_w = (const float*)d_in[2];
  const float* enc_attn_b = (const float*)d_in[3];
  const float* enc_ffn_w1 = (const float*)d_in[4];
  const float* enc_ffn_b1 = (const float*)d_in[5];
  const float* enc_ffn_w2 = (const float*)d_in[6];
  const float* enc_ffn_b2 = (const float*)d_in[7];
  const float* enc_ln_g   = (const float*)d_in[8];
  const float* enc_ln_b   = (const float*)d_in[9];
  const float* enc_fg     = (const float*)d_in[10];
  const float* enc_fb     = (const float*)d_in[11];
  const float* dec_self_w = (const float*)d_in[12];
  const float* dec_self_b = (const float*)d_in[13];
  const float* dec_src_w  = (const float*)d_in[14];
  const float* dec_src_b  = (const float*)d_in[15];
  const float* dec_ffn_w1 = (const float*)d_in[16];
  const float* dec_ffn_b1 = (const float*)d_in[17];
  const float* dec_ffn_w2 = (const float*)d_in[18];
  const float* dec_ffn_b2 = (const float*)d_in[19];
  const float* dec_ln_g   = (const float*)d_in[20];
  const float* dec_ln_b   = (const float*)d_in[21];
  const float* dec_fg     = (const float*)d_in[22];
  const float* dec_fb     = (const float*)d_in[23];
  const float* gen_w      = (const float*)d_in[24];
  const float* gen_b      = (const float*)d_in[25];
  const int*   src        = (const int*)d_in[26];
  const int*   tgt        = (const int*)d_in[27];
  const int*   src_mask   = (const int*)d_in[28];

  float* out = (float*)d_out;

  // ---- workspace ----
  char* wp = (char*)d_ws;
  auto alloc = [&](size_t bytes) { void* p = (void*)wp; wp += (bytes + 255) & ~(size_t)255; return p; };
  __bf16* TWea = (__bf16*)alloc(24ull * 262144 * 2);    // enc attn [6][4][512][512]^T
  __bf16* TWe1 = (__bf16*)alloc(6ull * 1048576 * 2);
  __bf16* TWe2 = (__bf16*)alloc(6ull * 1048576 * 2);
  __bf16* TWds = (__bf16*)alloc(24ull * 262144 * 2);
  __bf16* TWdx = (__bf16*)alloc(24ull * 262144 * 2);
  __bf16* TWd1 = (__bf16*)alloc(6ull * 1048576 * 2);
  __bf16* TWd2 = (__bf16*)alloc(6ull * 1048576 * 2);
  __bf16* Xb   = (__bf16*)alloc(4096ull * 512 * 2);     // bf16 residual stream
  __bf16* MEMb = (__bf16*)alloc(4096ull * 512 * 2);
  __bf16* Xs   = (__bf16*)alloc(4096ull * 512 * 2);     // residual sum (pre-LN)
  __bf16* qb   = (__bf16*)alloc(32ull * 1024 * 64 * 2); // } union with Fb
  __bf16* kb   = (__bf16*)alloc(32ull * 1024 * 64 * 2);
  __bf16* vt   = (__bf16*)alloc(32ull * 1024 * 64 * 2);
  __bf16* Ob   = (__bf16*)alloc(4096ull * 512 * 2);
  __bf16* Fb   = qb;                                    // ffn hidden bf16 [4096][2048]
  __bf16* GENT = TWea;                                  // gen_w^T, after encoder

  // ---- bulk weight transposes ----
  transpose_w_kernel<<<dim3(16, 16, 24), dim3(32, 8), 0, stream>>>(enc_attn_w, TWea, 512, 512);
  transpose_w_kernel<<<dim3(64, 16, 6),  dim3(32, 8), 0, stream>>>(enc_ffn_w1, TWe1, 512, 2048);
  transpose_w_kernel<<<dim3(16, 64, 6),  dim3(32, 8), 0, stream>>>(enc_ffn_w2, TWe2, 2048, 512);
  transpose_w_kernel<<<dim3(16, 16, 24), dim3(32, 8), 0, stream>>>(dec_self_w, TWds, 512, 512);
  transpose_w_kernel<<<dim3(16, 16, 24), dim3(32, 8), 0, stream>>>(dec_src_w,  TWdx, 512, 512);
  transpose_w_kernel<<<dim3(64, 16, 6),  dim3(32, 8), 0, stream>>>(dec_ffn_w1, TWd1, 512, 2048);
  transpose_w_kernel<<<dim3(16, 64, 6),  dim3(32, 8), 0, stream>>>(dec_ffn_w2, TWd2, 2048, 512);

  // attention sublayer: QKV -> flash -> O-proj(+residual). Then caller LNs.
  auto attention = [&](const __bf16* wt, const float* bptr, int causal,
                       const __bf16* Aq, const __bf16* Akv) {
    gemm2_kernel<2><<<dim3(32, 12), 256, 0, stream>>>(
        Aq, Akv, 512, wt, 512, nullptr, 0, bptr, 512, qb, kb, vt);
    if (causal)
      flash_kernel<1><<<dim3(16, 32), 256, 0, stream>>>(qb, kb, vt, nullptr, Ob);
    else
      flash_kernel<0><<<dim3(16, 32), 256, 0, stream>>>(qb, kb, vt, src_mask, Ob);
    gemm_kernel<<<dim3(32, 8), 256, 0, stream>>>(
        Ob, 512, wt + 3 * 262144, 512, Xb, Xs, 512, bptr + 3 * 512, 512);
  };

  auto ffn = [&](const __bf16* w1t, const float* b1, const __bf16* w2t, const float* b2) {
    gemm2_kernel<1><<<dim3(32, 16), 256, 0, stream>>>(
        Xb, Xb, 512, w1t, 512, Fb, 2048, b1, 512, nullptr, nullptr, nullptr);
    gemm_kernel<<<dim3(32, 8), 256, 0, stream>>>(
        Fb, 2048, w2t, 2048, Xb, Xs, 512, b2, 2048);
  };

  // ---------------- encoder ----------------
  embed_kernel<<<4096, 128, 0, stream>>>(src_emb, src, Xb);
  for (int i = 0; i < 6; i++) {
    attention(TWea + (long long)i * 1048576, enc_attn_b + i * 2048, 0, Xb, Xb);
    ln_kernel<<<1024, 256, 0, stream>>>(Xs, enc_ln_g + i * 1024, enc_ln_b + i * 1024, Xb);
    ffn(TWe1 + (long long)i * 1048576, enc_ffn_b1 + i * 2048,
        TWe2 + (long long)i * 1048576, enc_ffn_b2 + i * 512);
    ln_kernel<<<1024, 256, 0, stream>>>(Xs, enc_ln_g + i * 1024 + 512, enc_ln_b + i * 1024 + 512, Xb);
  }
  ln_kernel<<<1024, 256, 0, stream>>>(Xb, enc_fg, enc_fb, MEMb);

  transpose_w_kernel<<<dim3(1000, 16, 1), dim3(32, 8), 0, stream>>>(gen_w, GENT, 512, 32000);

  // ---------------- decoder ----------------
  embed_kernel<<<4096, 128, 0, stream>>>(tgt_emb, tgt, Xb);
  for (int i = 0; i < 6; i++) {
    attention(TWds + (long long)i * 1048576, dec_self_b + i * 2048, 1, Xb, Xb);
    ln_kernel<<<1024, 256, 0, stream>>>(Xs, dec_ln_g + i * 1536, dec_ln_b + i * 1536, Xb);

    attention(TWdx + (long long)i * 1048576, dec_src_b + i * 2048, 0, Xb, MEMb);
    ln_kernel<<<1024, 256, 0, stream>>>(Xs, dec_ln_g + i * 1536 + 512, dec_ln_b + i * 1536 + 512, Xb);

    ffn(TWd1 + (long long)i * 1048576, dec_ffn_b1 + i * 2048,
        TWd2 + (long long)i * 1048576, dec_ffn_b2 + i * 512);
    ln_kernel<<<1024, 256, 0, stream>>>(Xs, dec_ln_g + i * 1536 + 1024, dec_ln_b + i * 1536 + 1024, Xb);
  }
  ln_kernel<<<1024, 256, 0, stream>>>(Xb, dec_fg, dec_fb, Xb);

  // ---------------- generator: 256^2 8-wave 4-phase ----------------
  gemm256_kernel<<<dim3(16, 125), 512, 0, stream>>>(
      Xb, 512, GENT, 512, out, 32000, gen_b, 512);
}